// Round 2
// baseline (8524.409 us; speedup 1.0000x reference)
//
#include <hip/hip_runtime.h>
#include <hip/hip_bf16.h>

typedef __hip_bfloat16 bf16;

__device__ __forceinline__ float b2f(bf16 v) { return __bfloat162float(v); }
__device__ __forceinline__ float bits2f(unsigned short u) {
    return __uint_as_float(((unsigned)u) << 16);
}
__device__ __forceinline__ float invfreq(int jj) {
    // 10000^(-jj/36) = exp(-ln(10000)/36 * jj)
    return expf(-0.25584278811044955f * (float)jj);
}

// MODE 0: input tensor is bf16.  MODE 1: input tensor is float32.
template<int MODE>
__device__ __forceinline__ float ldin(const void* p, long i) {
    if (MODE == 0) return b2f(((const bf16*)p)[i]);
    else           return ((const float*)p)[i];
}

#define SCALE_ 0.11785113019775793f   // 72^-0.5

// ---------------- dtype detector: writes flag 0 (bf16) / 1 (f32) ----------------
__global__ void k_detect(const void* __restrict__ x, int* __restrict__ flag)
{
    const unsigned short* u = (const unsigned short*)x;
    int tid = threadIdx.x;
    int insane = 0;
    for (int i = tid; i < 2048; i += 64) {
        unsigned short s = u[i];
        int ex = (s >> 7) & 0xFF;
        if (ex >= 0xC5) insane++;   // |v| >= 2^70 or NaN/Inf as bf16 -> impossible for real bf16 data
    }
    #pragma unroll
    for (int off = 32; off > 0; off >>= 1) insane += __shfl_down(insane, off);
    if (tid == 0) flag[0] = (insane > 8) ? 1 : 0;
}

// ---------------- ada = silu(c4t) @ W_ada + b_ada ----------------
template<int MODE>
__global__ __launch_bounds__(256) void k_ada(const void* __restrict__ c4t,
    const void* __restrict__ W, const void* __restrict__ bias,
    float* __restrict__ ada, const int* __restrict__ flg)
{
    if (*flg != MODE) return;
    __shared__ float sv[1152];
    int b = blockIdx.x, tid = threadIdx.x;
    for (int i = tid; i < 1152; i += 256) {
        float v = ldin<MODE>(c4t, b * 1152 + i);
        sv[i] = v / (1.f + expf(-v));
    }
    __syncthreads();
    for (int j = tid; j < 6912; j += 256) {
        float acc = ldin<MODE>(bias, j);
        for (int k = 0; k < 1152; ++k)
            acc += sv[k] * ldin<MODE>(W, (long)k * 6912 + j);
        ada[b * 6912 + j] = acc;
    }
}

// ---------------- input -> f32 convert/copy ----------------
template<int MODE>
__global__ void k_cvt(const void* __restrict__ in, float* __restrict__ out, int n,
                      const int* __restrict__ flg)
{
    if (*flg != MODE) return;
    int i = blockIdx.x * 256 + threadIdx.x;
    if (i < n) out[i] = ldin<MODE>(in, i);
}

// ---------------- generic GEMM: A(f32 RxK) @ W(in-dtype KxN) [+bias][gelu] -> C(f32) ----------------
// Requires K % 16 == 0, N % 64 == 0.
template<int MODE>
__global__ __launch_bounds__(256) void k_gemm(
    const float* __restrict__ A, const void* __restrict__ W,
    const void* __restrict__ bias, float* __restrict__ C,
    int R, int K, int N, int act, const int* __restrict__ flg)
{
    if (*flg != MODE) return;
    __shared__ float As[16][64];   // [k][m]
    __shared__ float Bs[16][64];   // [k][n]
    int tid = threadIdx.x;
    int tx = tid & 15, ty = tid >> 4;
    int row0 = blockIdx.y << 6;
    int col0 = blockIdx.x << 6;
    float acc[4][4] = {};
    int ar = tid >> 2;           // 0..63 row within tile
    int ak = (tid & 3) << 2;     // 0,4,8,12 k offset
    int bk = tid >> 4;           // 0..15 k row
    int bc = (tid & 15) << 2;    // col offset
    for (int kt = 0; kt < K; kt += 16) {
        if (row0 + ar < R) {
            const float4 a4 = *(const float4*)(A + (long)(row0 + ar) * K + kt + ak);
            As[ak + 0][ar] = a4.x; As[ak + 1][ar] = a4.y;
            As[ak + 2][ar] = a4.z; As[ak + 3][ar] = a4.w;
        } else {
            As[ak + 0][ar] = 0.f; As[ak + 1][ar] = 0.f;
            As[ak + 2][ar] = 0.f; As[ak + 3][ar] = 0.f;
        }
        if (MODE == 0) {
            const ushort4 w4 = *(const ushort4*)((const unsigned short*)W + (long)(kt + bk) * N + col0 + bc);
            Bs[bk][bc + 0] = bits2f(w4.x); Bs[bk][bc + 1] = bits2f(w4.y);
            Bs[bk][bc + 2] = bits2f(w4.z); Bs[bk][bc + 3] = bits2f(w4.w);
        } else {
            const float4 w4 = *(const float4*)((const float*)W + (long)(kt + bk) * N + col0 + bc);
            Bs[bk][bc + 0] = w4.x; Bs[bk][bc + 1] = w4.y;
            Bs[bk][bc + 2] = w4.z; Bs[bk][bc + 3] = w4.w;
        }
        __syncthreads();
        #pragma unroll
        for (int kk = 0; kk < 16; ++kk) {
            float4 av = *(const float4*)&As[kk][ty << 2];
            float4 bv = *(const float4*)&Bs[kk][tx << 2];
            float a[4] = {av.x, av.y, av.z, av.w};
            float b[4] = {bv.x, bv.y, bv.z, bv.w};
            #pragma unroll
            for (int i = 0; i < 4; ++i)
                #pragma unroll
                for (int j = 0; j < 4; ++j)
                    acc[i][j] += a[i] * b[j];
        }
        __syncthreads();
    }
    #pragma unroll
    for (int i = 0; i < 4; ++i) {
        int gr = row0 + (ty << 2) + i;
        if (gr >= R) continue;
        float* cp = C + (long)gr * N + col0 + (tx << 2);
        #pragma unroll
        for (int j = 0; j < 4; ++j) {
            float v = acc[i][j];
            if (bias) v += ldin<MODE>(bias, col0 + (tx << 2) + j);
            if (act) {
                float xx = v;
                float inner = 0.7978845608028654f * (xx + 0.044715f * xx * xx * xx);
                v = 0.5f * xx * (1.f + tanhf(inner));
            }
            cp[j] = v;
        }
    }
}

// ---------------- LN (temporal): x rows (b,t,n) -> out f32 rows (b,n,t), *tn_w + tn_b ----------------
template<int MODE>
__global__ __launch_bounds__(256) void k_ln_t(
    const void* __restrict__ x, const void* __restrict__ w,
    const void* __restrict__ bb, float* __restrict__ out,
    const int* __restrict__ flg)
{
    if (*flg != MODE) return;
    int r = blockIdx.x;               // (b*16+t)*256 + n
    int n = r & 255;
    int bt = r >> 8;
    int b = bt >> 4, t = bt & 15;
    long orow = (long)((b << 8) + n) * 16 + t;
    int tid = threadIdx.x;
    float vals[5];
    float s = 0.f, ss = 0.f;
    int c = 0;
    for (int i = tid; i < 1152; i += 256, ++c) {
        float v = ldin<MODE>(x, (long)r * 1152 + i);
        vals[c] = v; s += v; ss += v * v;
    }
    #pragma unroll
    for (int off = 32; off > 0; off >>= 1) {
        s  += __shfl_down(s, off);
        ss += __shfl_down(ss, off);
    }
    __shared__ float rs[4], rss[4];
    int wid = tid >> 6;
    if ((tid & 63) == 0) { rs[wid] = s; rss[wid] = ss; }
    __syncthreads();
    float S  = rs[0] + rs[1] + rs[2] + rs[3];
    float SS = rss[0] + rss[1] + rss[2] + rss[3];
    float mu = S * (1.f / 1152.f);
    float var = SS * (1.f / 1152.f) - mu * mu;
    float rstd = rsqrtf(var + 1e-5f);
    c = 0;
    float* op = out + orow * 1152;
    for (int i = tid; i < 1152; i += 256, ++c)
        op[i] = (vals[c] - mu) * rstd * ldin<MODE>(w, i) + ldin<MODE>(bb, i);
}

// ---------------- LN + adaLN modulation: x4 f32 -> out f32 (rows aligned) — mode-free ----------------
__global__ __launch_bounds__(256) void k_ln_mod(
    const float* __restrict__ x4, const float* __restrict__ ada,
    int psh, int psc, float eps, float* __restrict__ out)
{
    int r = blockIdx.x;
    int b = r >> 12;                  // r / (16*256)
    const float* xp = x4 + (long)r * 1152;
    int tid = threadIdx.x;
    float vals[5];
    float s = 0.f, ss = 0.f;
    int c = 0;
    for (int i = tid; i < 1152; i += 256, ++c) {
        float v = xp[i];
        vals[c] = v; s += v; ss += v * v;
    }
    #pragma unroll
    for (int off = 32; off > 0; off >>= 1) {
        s  += __shfl_down(s, off);
        ss += __shfl_down(ss, off);
    }
    __shared__ float rs[4], rss[4];
    int wid = tid >> 6;
    if ((tid & 63) == 0) { rs[wid] = s; rss[wid] = ss; }
    __syncthreads();
    float S  = rs[0] + rs[1] + rs[2] + rs[3];
    float SS = rss[0] + rss[1] + rss[2] + rss[3];
    float mu = S * (1.f / 1152.f);
    float var = SS * (1.f / 1152.f) - mu * mu;
    float rstd = rsqrtf(var + eps);
    const float* sh = ada + (b * 6 + psh) * 1152;
    const float* sc = ada + (b * 6 + psc) * 1152;
    c = 0;
    float* op = out + (long)r * 1152;
    for (int i = tid; i < 1152; i += 256, ++c)
        op[i] = (vals[c] - mu) * rstd * (1.f + sc[i]) + sh[i];
}

// ---------------- temporal attention (one block per (b,n,h)) — mode-free ----------------
__global__ __launch_bounds__(256) void k_attn_t(
    const float* __restrict__ qkv, const float* __restrict__ ekt,
    const float* __restrict__ evt, const int* __restrict__ f,
    float* __restrict__ out)
{
    __shared__ float qs[16][72], ks[32][72], vs[32][72], sc[16][33];
    int blk = blockIdx.x;             // (b*256+n)*16 + h
    int h = blk & 15;
    int bn = blk >> 4;                // b*256 + n
    int b = bn >> 8;
    int tid = threadIdx.x;
    long qbase = (long)bn * 16 * 3456 + h * 72;
    for (int idx = tid; idx < 16 * 72; idx += 256) {
        int i = idx / 72, d = idx - i * 72;
        long p0 = qbase + (long)i * 3456;
        float v  = qkv[p0 + d];
        float v2 = qkv[p0 + (d ^ 1)];
        float ang = (float)f[i] * invfreq(d >> 1);
        float sn, cs; sincosf(ang, &sn, &cs);
        float rv = (d & 1) ? (v * cs + v2 * sn) : (v * cs - v2 * sn);
        qs[i][d] = rv * SCALE_;
    }
    for (int idx = tid; idx < 32 * 72; idx += 256) {
        int j = idx / 72, d = idx - j * 72;
        float kv, kv2, vv; int pi;
        if (j < 16) {
            long base = (long)(b * 16 + j) * 1152 + h * 72;
            kv  = ekt[base + d];
            kv2 = ekt[base + (d ^ 1)];
            vv  = evt[base + d];
            pi = j;
        } else {
            int jj = j - 16;
            long base = qbase + (long)jj * 3456;
            kv  = qkv[base + 1152 + d];
            kv2 = qkv[base + 1152 + (d ^ 1)];
            vv  = qkv[base + 2304 + d];
            pi = jj;
        }
        float ang = (float)f[pi] * invfreq(d >> 1);
        float sn, cs; sincosf(ang, &sn, &cs);
        ks[j][d] = (d & 1) ? (kv * cs + kv2 * sn) : (kv * cs - kv2 * sn);
        vs[j][d] = vv;
    }
    __syncthreads();
    for (int e = tid; e < 512; e += 256) {
        int i = e >> 5, j = e & 31;
        float s = 0.f;
        for (int d = 0; d < 72; ++d) s += qs[i][d] * ks[j][d];
        sc[i][j] = s;
    }
    __syncthreads();
    if (tid < 16) {
        float m = -1e30f;
        for (int j = 0; j < 32; ++j) m = fmaxf(m, sc[tid][j]);
        float l = 0.f;
        for (int j = 0; j < 32; ++j) { float p = expf(sc[tid][j] - m); sc[tid][j] = p; l += p; }
        float inv = 1.f / l;
        for (int j = 0; j < 32; ++j) sc[tid][j] *= inv;
    }
    __syncthreads();
    for (int idx = tid; idx < 16 * 72; idx += 256) {
        int i = idx / 72, d = idx - i * 72;
        float o = 0.f;
        for (int j = 0; j < 32; ++j) o += sc[i][j] * vs[j][d];
        out[((long)bn * 16 + i) * 1152 + h * 72 + d] = o;
    }
}

// ---------------- spatial attention (one block per (b,t,h, 64-row chunk)) — mode-free ----------------
__global__ __launch_bounds__(256) void k_attn_s(
    const float* __restrict__ qkv, const float* __restrict__ eks,
    const float* __restrict__ evs, float* __restrict__ out)
{
    __shared__ float qs[64][72];
    __shared__ float ks[32][72];
    __shared__ float vs[32][72];
    __shared__ float ps[64][33];
    __shared__ float ralpha[64];
    __shared__ float rl[64];
    int blk = blockIdx.x;             // ((b*16+t)*16 + h)*4 + ic
    int ic = blk & 3;
    int bth = blk >> 2;
    int h = bth & 15;
    int bt = bth >> 4;                // b*16 + t
    int tid = threadIdx.x;
    int ri = tid >> 2;                // 0..63 row
    int dg = (tid & 3) * 18;          // d-group offset
    long qkvrow0 = (long)bt * 256;    // row (b*16+t)*256
    for (int idx = tid; idx < 64 * 72; idx += 256) {
        int i = idx / 72, d = idx - i * 72;
        qs[i][d] = qkv[(qkvrow0 + ic * 64 + i) * 3456 + h * 72 + d] * SCALE_;
    }
    float acc[18];
    #pragma unroll
    for (int e = 0; e < 18; ++e) acc[e] = 0.f;
    float m = -1e30f, l = 0.f;        // valid on threads tid<64 (leader of row tid)
    for (int jc = 0; jc < 257; jc += 32) {
        int jn = min(32, 257 - jc);
        for (int idx = tid; idx < jn * 72; idx += 256) {
            int j = idx / 72, d = idx - j * 72;
            int gj = jc + j;
            float kv, vv;
            if (gj == 0) {
                kv = eks[(long)bt * 1152 + h * 72 + d];
                vv = evs[(long)bt * 1152 + h * 72 + d];
            } else {
                long base = (qkvrow0 + gj - 1) * 3456 + h * 72 + d;
                kv = qkv[base + 1152];
                vv = qkv[base + 2304];
            }
            ks[j][d] = kv; vs[j][d] = vv;
        }
        __syncthreads();
        for (int e = tid; e < 64 * 32; e += 256) {
            int i = e >> 5, j = e & 31;
            float s = -1e30f;
            if (j < jn) {
                s = 0.f;
                for (int d = 0; d < 72; ++d) s += qs[i][d] * ks[j][d];
            }
            ps[i][j] = s;
        }
        __syncthreads();
        if (tid < 64) {
            float cm = m;
            for (int j = 0; j < jn; ++j) cm = fmaxf(cm, ps[tid][j]);
            float alpha = expf(m - cm);
            float sum = 0.f;
            for (int j = 0; j < jn; ++j) { float p = expf(ps[tid][j] - cm); ps[tid][j] = p; sum += p; }
            l = l * alpha + sum;
            m = cm;
            ralpha[tid] = alpha;
            rl[tid] = l;
        }
        __syncthreads();
        float alpha = ralpha[ri];
        #pragma unroll
        for (int e = 0; e < 18; ++e) acc[e] *= alpha;
        for (int j = 0; j < jn; ++j) {
            float p = ps[ri][j];
            #pragma unroll
            for (int e = 0; e < 18; ++e) acc[e] += p * vs[j][dg + e];
        }
        __syncthreads();
    }
    float invl = 1.f / rl[ri];
    long orow = qkvrow0 + ic * 64 + ri;
    #pragma unroll
    for (int e = 0; e < 18; ++e)
        out[orow * 1152 + h * 72 + dg + e] = acc[e] * invl;
}

// ---------------- x4 = x + res (res rows are (b,n,t)) ----------------
template<int MODE>
__global__ __launch_bounds__(256) void k_add_t(
    const void* __restrict__ x, const float* __restrict__ res,
    float* __restrict__ x4, const int* __restrict__ flg)
{
    if (*flg != MODE) return;
    int idx = blockIdx.x * 256 + threadIdx.x;   // < 9437184
    int r = idx / 1152;
    int mcol = idx - r * 1152;
    int n = r & 255;
    int bt = r >> 8;
    int b = bt >> 4, t = bt & 15;
    long r2 = (long)((b << 8) + n) * 16 + t;
    x4[idx] = ldin<MODE>(x, idx) + res[r2 * 1152 + mcol];
}

// ---------------- x4 += gate * y ; optionally emit output (in-dtype) ----------------
template<int MODE>
__global__ __launch_bounds__(256) void k_add_g(
    float* __restrict__ x4, const float* __restrict__ y,
    const float* __restrict__ ada, int part, void* __restrict__ outp,
    const int* __restrict__ flg)
{
    if (*flg != MODE) return;
    int idx = blockIdx.x * 256 + threadIdx.x;
    int r = idx / 1152;
    int mcol = idx - r * 1152;
    int b = r >> 12;
    float g = ada[(b * 6 + part) * 1152 + mcol];
    float v = x4[idx] + g * y[idx];
    x4[idx] = v;
    if (outp) {
        if (MODE == 0) ((bf16*)outp)[idx] = __float2bfloat16(v);
        else           ((float*)outp)[idx] = v;
    }
}

extern "C" void kernel_launch(void* const* d_in, const int* in_sizes, int n_in,
                              void* d_out, int out_size, void* d_ws, size_t ws_size,
                              hipStream_t stream)
{
    const void* x      = d_in[0];
    const void* c4t    = d_in[1];
    const void* c      = d_in[2];
    const void* W_ada  = d_in[3];
    const void* b_ada  = d_in[4];
    const void* tn_w   = d_in[5];
    const void* tn_b   = d_in[6];
    const void* t_qkv  = d_in[7];
    const void* t_k    = d_in[8];
    const void* t_v    = d_in[9];
    const void* t_outw = d_in[10];
    const void* t_fcw  = d_in[11];
    const void* t_fcb  = d_in[12];
    const void* s_qkv  = d_in[13];
    const void* s_k    = d_in[14];
    const void* s_v    = d_in[15];
    const void* s_outw = d_in[16];
    const void* mlp_w1 = d_in[17];
    const void* mlp_b1 = d_in[18];
    const void* mlp_w2 = d_in[19];
    const void* mlp_b2 = d_in[20];
    const int*  f      = (const int*)d_in[21];

    float* ws   = (float*)d_ws;
    float* x4   = ws;                       // 9437184
    float* buf1 = x4   + 9437184;           // 37748736 (qkv / h / proj outs)
    float* buf2 = buf1 + 37748736;          // 9437184
    float* ada  = buf2 + 9437184;           // 13824
    float* cf32 = ada  + 13824;             // 36864
    float* ekt  = cf32 + 36864;             // 36864
    float* evt  = ekt  + 36864;             // 36864
    float* eks  = evt  + 36864;             // 36864
    float* evs  = eks  + 36864;             // 36864
    int*   flg  = (int*)(evs + 36864);      // 1 int

    k_detect<<<1, 64, 0, stream>>>(x, flg);

    // modulation + context projections (both modes launched; inactive returns immediately)
    k_ada<0><<<2, 256, 0, stream>>>(c4t, W_ada, b_ada, ada, flg);
    k_ada<1><<<2, 256, 0, stream>>>(c4t, W_ada, b_ada, ada, flg);
    k_cvt<0><<<144, 256, 0, stream>>>(c, cf32, 36864, flg);
    k_cvt<1><<<144, 256, 0, stream>>>(c, cf32, 36864, flg);
    k_gemm<0><<<dim3(18, 1), 256, 0, stream>>>(cf32, t_k, nullptr, ekt, 32, 1152, 1152, 0, flg);
    k_gemm<1><<<dim3(18, 1), 256, 0, stream>>>(cf32, t_k, nullptr, ekt, 32, 1152, 1152, 0, flg);
    k_gemm<0><<<dim3(18, 1), 256, 0, stream>>>(cf32, t_v, nullptr, evt, 32, 1152, 1152, 0, flg);
    k_gemm<1><<<dim3(18, 1), 256, 0, stream>>>(cf32, t_v, nullptr, evt, 32, 1152, 1152, 0, flg);
    k_gemm<0><<<dim3(18, 1), 256, 0, stream>>>(cf32, s_k, nullptr, eks, 32, 1152, 1152, 0, flg);
    k_gemm<1><<<dim3(18, 1), 256, 0, stream>>>(cf32, s_k, nullptr, eks, 32, 1152, 1152, 0, flg);
    k_gemm<0><<<dim3(18, 1), 256, 0, stream>>>(cf32, s_v, nullptr, evs, 32, 1152, 1152, 0, flg);
    k_gemm<1><<<dim3(18, 1), 256, 0, stream>>>(cf32, s_v, nullptr, evs, 32, 1152, 1152, 0, flg);

    // ---- temporal attention ----
    k_ln_t<0><<<8192, 256, 0, stream>>>(x, tn_w, tn_b, buf2, flg);
    k_ln_t<1><<<8192, 256, 0, stream>>>(x, tn_w, tn_b, buf2, flg);
    k_gemm<0><<<dim3(54, 128), 256, 0, stream>>>(buf2, t_qkv, nullptr, buf1, 8192, 1152, 3456, 0, flg);
    k_gemm<1><<<dim3(54, 128), 256, 0, stream>>>(buf2, t_qkv, nullptr, buf1, 8192, 1152, 3456, 0, flg);
    k_attn_t<<<8192, 256, 0, stream>>>(buf1, ekt, evt, f, buf2);
    k_gemm<0><<<dim3(18, 128), 256, 0, stream>>>(buf2, t_outw, nullptr, buf1, 8192, 1152, 1152, 0, flg);
    k_gemm<1><<<dim3(18, 128), 256, 0, stream>>>(buf2, t_outw, nullptr, buf1, 8192, 1152, 1152, 0, flg);
    k_gemm<0><<<dim3(18, 128), 256, 0, stream>>>(buf1, t_fcw, t_fcb, buf2, 8192, 1152, 1152, 0, flg);
    k_gemm<1><<<dim3(18, 128), 256, 0, stream>>>(buf1, t_fcw, t_fcb, buf2, 8192, 1152, 1152, 0, flg);
    k_add_t<0><<<36864, 256, 0, stream>>>(x, buf2, x4, flg);
    k_add_t<1><<<36864, 256, 0, stream>>>(x, buf2, x4, flg);

    // ---- spatial attention ----
    k_ln_mod<<<8192, 256, 0, stream>>>(x4, ada, 0, 1, 1e-6f, buf2);
    k_gemm<0><<<dim3(54, 128), 256, 0, stream>>>(buf2, s_qkv, nullptr, buf1, 8192, 1152, 3456, 0, flg);
    k_gemm<1><<<dim3(54, 128), 256, 0, stream>>>(buf2, s_qkv, nullptr, buf1, 8192, 1152, 3456, 0, flg);
    k_attn_s<<<2048, 256, 0, stream>>>(buf1, eks, evs, buf2);
    k_gemm<0><<<dim3(18, 128), 256, 0, stream>>>(buf2, s_outw, nullptr, buf1, 8192, 1152, 1152, 0, flg);
    k_gemm<1><<<dim3(18, 128), 256, 0, stream>>>(buf2, s_outw, nullptr, buf1, 8192, 1152, 1152, 0, flg);
    k_add_g<0><<<36864, 256, 0, stream>>>(x4, buf1, ada, 2, nullptr, flg);
    k_add_g<1><<<36864, 256, 0, stream>>>(x4, buf1, ada, 2, nullptr, flg);

    // ---- MLP ----
    k_ln_mod<<<8192, 256, 0, stream>>>(x4, ada, 3, 4, 1e-6f, buf2);
    k_gemm<0><<<dim3(72, 128), 256, 0, stream>>>(buf2, mlp_w1, mlp_b1, buf1, 8192, 1152, 4608, 1, flg);
    k_gemm<1><<<dim3(72, 128), 256, 0, stream>>>(buf2, mlp_w1, mlp_b1, buf1, 8192, 1152, 4608, 1, flg);
    k_gemm<0><<<dim3(18, 128), 256, 0, stream>>>(buf1, mlp_w2, mlp_b2, buf2, 8192, 4608, 1152, 0, flg);
    k_gemm<1><<<dim3(18, 128), 256, 0, stream>>>(buf1, mlp_w2, mlp_b2, buf2, 8192, 4608, 1152, 0, flg);
    k_add_g<0><<<36864, 256, 0, stream>>>(x4, buf2, ada, 5, d_out, flg);
    k_add_g<1><<<36864, 256, 0, stream>>>(x4, buf2, ada, 5, d_out, flg);
}

// Round 3
// 2664.509 us; speedup vs baseline: 3.1992x; 3.1992x over previous
//
#include <hip/hip_runtime.h>
#include <hip/hip_bf16.h>

typedef __hip_bfloat16 bf16;
typedef __attribute__((ext_vector_type(8))) short short8;
typedef __attribute__((ext_vector_type(4))) float floatx4;

__device__ __forceinline__ float b2f(bf16 v) { return __bfloat162float(v); }
__device__ __forceinline__ float invfreq(int jj) {
    return expf(-0.25584278811044955f * (float)jj);   // 10000^(-jj/36)
}

// MODE 0: input tensor is bf16.  MODE 1: input tensor is float32.
template<int MODE>
__device__ __forceinline__ float ldin(const void* p, long i) {
    if (MODE == 0) return b2f(((const bf16*)p)[i]);
    else           return ((const float*)p)[i];
}

#define SCALE_ 0.11785113019775793f   // 72^-0.5

// async global->LDS, 16B per lane; LDS dest is wave-uniform base + lane*16
#define GLDS(gp, lp) __builtin_amdgcn_global_load_lds( \
    (const __attribute__((address_space(1))) void*)(gp), \
    (__attribute__((address_space(3))) void*)(lp), 16, 0, 0)

// ---------------- dtype detector ----------------
__global__ void k_detect(const void* __restrict__ x, int* __restrict__ flag)
{
    const unsigned short* u = (const unsigned short*)x;
    int tid = threadIdx.x;
    int insane = 0;
    for (int i = tid; i < 2048; i += 64) {
        unsigned short s = u[i];
        int ex = (s >> 7) & 0xFF;
        if (ex >= 0xC5) insane++;
    }
    #pragma unroll
    for (int off = 32; off > 0; off >>= 1) insane += __shfl_down(insane, off);
    if (tid == 0) flag[0] = (insane > 8) ? 1 : 0;
}

// ---------------- silu(c4t) -> f32 ----------------
template<int MODE>
__global__ void k_silu(const void* __restrict__ c4t, float* __restrict__ out,
                       const int* __restrict__ flg)
{
    if (*flg != MODE) return;
    int i = blockIdx.x * 256 + threadIdx.x;
    if (i < 2304) {
        float v = ldin<MODE>(c4t, i);
        out[i] = v / (1.f + expf(-v));
    }
}

// ---------------- input -> f32 convert/copy ----------------
template<int MODE>
__global__ void k_cvt(const void* __restrict__ in, float* __restrict__ out, int n,
                      const int* __restrict__ flg)
{
    if (*flg != MODE) return;
    int i = blockIdx.x * 256 + threadIdx.x;
    if (i < n) out[i] = ldin<MODE>(in, i);
}

// ---------------- weight transpose+convert: W (KxN, in dtype) -> Wt (NxK bf16) ----------------
template<int MODE>
__global__ __launch_bounds__(256) void k_wt(const void* __restrict__ W,
    bf16* __restrict__ Wt, int K, int N, const int* __restrict__ flg)
{
    if (*flg != MODE) return;
    __shared__ float tile[32][33];
    int n0 = blockIdx.x << 5, k0 = blockIdx.y << 5;
    int tid = threadIdx.x;
    int r = tid >> 3, c4 = (tid & 7) << 2;
    long base = (long)(k0 + r) * N + n0 + c4;
    #pragma unroll
    for (int i = 0; i < 4; ++i) tile[r][c4 + i] = ldin<MODE>(W, base + i);
    __syncthreads();
    long obase = (long)(n0 + r) * K + k0 + c4;
    #pragma unroll
    for (int i = 0; i < 4; ++i) Wt[obase + i] = __float2bfloat16(tile[c4 + i][r]);
}

// ---------------- small f32 GEMM (kept for ada + context projections) ----------------
template<int MODE>
__global__ __launch_bounds__(256) void k_gemm(
    const float* __restrict__ A, const void* __restrict__ W,
    const void* __restrict__ bias, float* __restrict__ C,
    int R, int K, int N, int act, const int* __restrict__ flg)
{
    if (*flg != MODE) return;
    __shared__ float As[16][64];
    __shared__ float Bs[16][64];
    int tid = threadIdx.x;
    int tx = tid & 15, ty = tid >> 4;
    int row0 = blockIdx.y << 6;
    int col0 = blockIdx.x << 6;
    float acc[4][4] = {};
    int ar = tid >> 2;
    int ak = (tid & 3) << 2;
    int bk = tid >> 4;
    int bc = (tid & 15) << 2;
    for (int kt = 0; kt < K; kt += 16) {
        if (row0 + ar < R) {
            const float4 a4 = *(const float4*)(A + (long)(row0 + ar) * K + kt + ak);
            As[ak + 0][ar] = a4.x; As[ak + 1][ar] = a4.y;
            As[ak + 2][ar] = a4.z; As[ak + 3][ar] = a4.w;
        } else {
            As[ak + 0][ar] = 0.f; As[ak + 1][ar] = 0.f;
            As[ak + 2][ar] = 0.f; As[ak + 3][ar] = 0.f;
        }
        #pragma unroll
        for (int i = 0; i < 4; ++i)
            Bs[bk][bc + i] = ldin<MODE>(W, (long)(kt + bk) * N + col0 + bc + i);
        __syncthreads();
        #pragma unroll
        for (int kk = 0; kk < 16; ++kk) {
            float4 av = *(const float4*)&As[kk][ty << 2];
            float4 bv = *(const float4*)&Bs[kk][tx << 2];
            float a[4] = {av.x, av.y, av.z, av.w};
            float b[4] = {bv.x, bv.y, bv.z, bv.w};
            #pragma unroll
            for (int i = 0; i < 4; ++i)
                #pragma unroll
                for (int j = 0; j < 4; ++j)
                    acc[i][j] += a[i] * b[j];
        }
        __syncthreads();
    }
    #pragma unroll
    for (int i = 0; i < 4; ++i) {
        int gr = row0 + (ty << 2) + i;
        if (gr >= R) continue;
        float* cp = C + (long)gr * N + col0 + (tx << 2);
        #pragma unroll
        for (int j = 0; j < 4; ++j) {
            float v = acc[i][j];
            if (bias) v += ldin<MODE>(bias, col0 + (tx << 2) + j);
            cp[j] = v;
        }
    }
}

// ---------------- MFMA GEMM: A(bf16 Mx K) @ Wt(bf16 NxK)^T -> C ----------------
// M%128==0, N%128==0, K%32==0. 256 thr = 4 waves in 2x2, each wave 64x64.
__global__ __launch_bounds__(256) void k_mgemm(
    const bf16* __restrict__ A, const bf16* __restrict__ Wt,
    const float* __restrict__ bias, void* __restrict__ Cout,
    int K, int N, int outbf, int act)
{
    __shared__ short As[4096];   // 8 m-tiles * 512 shorts (frag-linear)
    __shared__ short Bs[4096];   // 8 n-tiles * 512
    int tid = threadIdx.x;
    int lane = tid & 63, wave = tid >> 6;
    int mq = wave >> 1, nq = wave & 1;
    long row0 = (long)blockIdx.y << 7;
    long col0 = (long)blockIdx.x << 7;
    int mi = lane & 15, q = lane >> 4;

    const bf16* gA0 = A  + (row0 + (2 * wave) * 16 + mi) * K + q * 8;
    const bf16* gA1 = A  + (row0 + (2 * wave + 1) * 16 + mi) * K + q * 8;
    const bf16* gB0 = Wt + (col0 + (2 * wave) * 16 + mi) * K + q * 8;
    const bf16* gB1 = Wt + (col0 + (2 * wave + 1) * 16 + mi) * K + q * 8;
    short* lA0 = &As[(2 * wave) * 512];
    short* lA1 = &As[(2 * wave + 1) * 512];
    short* lB0 = &Bs[(2 * wave) * 512];
    short* lB1 = &Bs[(2 * wave + 1) * 512];

    floatx4 acc[4][4] = {};

    for (int kt = 0; kt < K; kt += 32) {
        GLDS(gA0 + kt, lA0);
        GLDS(gA1 + kt, lA1);
        GLDS(gB0 + kt, lB0);
        GLDS(gB1 + kt, lB1);
        __syncthreads();
        short8 af[4], bfr[4];
        #pragma unroll
        for (int i = 0; i < 4; ++i)
            af[i] = *(const short8*)&As[(4 * mq + i) * 512 + lane * 8];
        #pragma unroll
        for (int j = 0; j < 4; ++j)
            bfr[j] = *(const short8*)&Bs[(4 * nq + j) * 512 + lane * 8];
        #pragma unroll
        for (int i = 0; i < 4; ++i)
            #pragma unroll
            for (int j = 0; j < 4; ++j)
                acc[i][j] = __builtin_amdgcn_mfma_f32_16x16x32_bf16(
                    af[i], bfr[j], acc[i][j], 0, 0, 0);
        __syncthreads();
    }

    int lr = lane >> 4, lc = lane & 15;
    #pragma unroll
    for (int i = 0; i < 4; ++i) {
        #pragma unroll
        for (int r = 0; r < 4; ++r) {
            long grow = row0 + mq * 64 + i * 16 + lr * 4 + r;
            #pragma unroll
            for (int j = 0; j < 4; ++j) {
                int col = (int)col0 + nq * 64 + j * 16 + lc;
                float v = acc[i][j][r];
                if (bias) v += bias[col];
                if (act) {
                    float xx = v;
                    float inner = 0.7978845608028654f * (xx + 0.044715f * xx * xx * xx);
                    v = 0.5f * xx * (1.f + tanhf(inner));
                }
                if (outbf) ((bf16*)Cout)[grow * N + col] = __float2bfloat16(v);
                else       ((float*)Cout)[grow * N + col] = v;
            }
        }
    }
}

// ---------------- LN (temporal): x rows (b,t,n) -> bf16 rows (b,n,t) ----------------
template<int MODE>
__global__ __launch_bounds__(256) void k_ln_t(
    const void* __restrict__ x, const void* __restrict__ w,
    const void* __restrict__ bb, bf16* __restrict__ out,
    const int* __restrict__ flg)
{
    if (*flg != MODE) return;
    int r = blockIdx.x;
    int n = r & 255;
    int bt = r >> 8;
    int b = bt >> 4, t = bt & 15;
    long orow = (long)((b << 8) + n) * 16 + t;
    int tid = threadIdx.x;
    float vals[5];
    float s = 0.f, ss = 0.f;
    int c = 0;
    for (int i = tid; i < 1152; i += 256, ++c) {
        float v = ldin<MODE>(x, (long)r * 1152 + i);
        vals[c] = v; s += v; ss += v * v;
    }
    #pragma unroll
    for (int off = 32; off > 0; off >>= 1) {
        s  += __shfl_down(s, off);
        ss += __shfl_down(ss, off);
    }
    __shared__ float rs[4], rss[4];
    int wid = tid >> 6;
    if ((tid & 63) == 0) { rs[wid] = s; rss[wid] = ss; }
    __syncthreads();
    float S  = rs[0] + rs[1] + rs[2] + rs[3];
    float SS = rss[0] + rss[1] + rss[2] + rss[3];
    float mu = S * (1.f / 1152.f);
    float var = SS * (1.f / 1152.f) - mu * mu;
    float rstd = rsqrtf(var + 1e-5f);
    c = 0;
    bf16* op = out + orow * 1152;
    for (int i = tid; i < 1152; i += 256, ++c)
        op[i] = __float2bfloat16((vals[c] - mu) * rstd * ldin<MODE>(w, i) + ldin<MODE>(bb, i));
}

// ---------------- LN + adaLN modulation: x4 f32 -> bf16 ----------------
__global__ __launch_bounds__(256) void k_ln_mod(
    const float* __restrict__ x4, const float* __restrict__ ada,
    int psh, int psc, float eps, bf16* __restrict__ out)
{
    int r = blockIdx.x;
    int b = r >> 12;
    const float* xp = x4 + (long)r * 1152;
    int tid = threadIdx.x;
    float vals[5];
    float s = 0.f, ss = 0.f;
    int c = 0;
    for (int i = tid; i < 1152; i += 256, ++c) {
        float v = xp[i];
        vals[c] = v; s += v; ss += v * v;
    }
    #pragma unroll
    for (int off = 32; off > 0; off >>= 1) {
        s  += __shfl_down(s, off);
        ss += __shfl_down(ss, off);
    }
    __shared__ float rs[4], rss[4];
    int wid = tid >> 6;
    if ((tid & 63) == 0) { rs[wid] = s; rss[wid] = ss; }
    __syncthreads();
    float S  = rs[0] + rs[1] + rs[2] + rs[3];
    float SS = rss[0] + rss[1] + rss[2] + rss[3];
    float mu = S * (1.f / 1152.f);
    float var = SS * (1.f / 1152.f) - mu * mu;
    float rstd = rsqrtf(var + eps);
    const float* sh = ada + (b * 6 + psh) * 1152;
    const float* sc = ada + (b * 6 + psc) * 1152;
    c = 0;
    bf16* op = out + (long)r * 1152;
    for (int i = tid; i < 1152; i += 256, ++c)
        op[i] = __float2bfloat16((vals[c] - mu) * rstd * (1.f + sc[i]) + sh[i]);
}

// ---------------- temporal attention (qkv bf16, out bf16) ----------------
__global__ __launch_bounds__(256) void k_attn_t(
    const bf16* __restrict__ qkv, const float* __restrict__ ekt,
    const float* __restrict__ evt, const int* __restrict__ f,
    bf16* __restrict__ out)
{
    __shared__ float qs[16][72], ks[32][72], vs[32][72], sc[16][33];
    int blk = blockIdx.x;
    int h = blk & 15;
    int bn = blk >> 4;
    int b = bn >> 8;
    int tid = threadIdx.x;
    long qbase = (long)bn * 16 * 3456 + h * 72;
    for (int idx = tid; idx < 16 * 72; idx += 256) {
        int i = idx / 72, d = idx - i * 72;
        long p0 = qbase + (long)i * 3456;
        float v  = b2f(qkv[p0 + d]);
        float v2 = b2f(qkv[p0 + (d ^ 1)]);
        float ang = (float)f[i] * invfreq(d >> 1);
        float sn, cs; sincosf(ang, &sn, &cs);
        float rv = (d & 1) ? (v * cs + v2 * sn) : (v * cs - v2 * sn);
        qs[i][d] = rv * SCALE_;
    }
    for (int idx = tid; idx < 32 * 72; idx += 256) {
        int j = idx / 72, d = idx - j * 72;
        float kv, kv2, vv; int pi;
        if (j < 16) {
            long base = (long)(b * 16 + j) * 1152 + h * 72;
            kv  = ekt[base + d];
            kv2 = ekt[base + (d ^ 1)];
            vv  = evt[base + d];
            pi = j;
        } else {
            int jj = j - 16;
            long base = qbase + (long)jj * 3456;
            kv  = b2f(qkv[base + 1152 + d]);
            kv2 = b2f(qkv[base + 1152 + (d ^ 1)]);
            vv  = b2f(qkv[base + 2304 + d]);
            pi = jj;
        }
        float ang = (float)f[pi] * invfreq(d >> 1);
        float sn, cs; sincosf(ang, &sn, &cs);
        ks[j][d] = (d & 1) ? (kv * cs + kv2 * sn) : (kv * cs - kv2 * sn);
        vs[j][d] = vv;
    }
    __syncthreads();
    for (int e = tid; e < 512; e += 256) {
        int i = e >> 5, j = e & 31;
        float s = 0.f;
        for (int d = 0; d < 72; ++d) s += qs[i][d] * ks[j][d];
        sc[i][j] = s;
    }
    __syncthreads();
    if (tid < 16) {
        float m = -1e30f;
        for (int j = 0; j < 32; ++j) m = fmaxf(m, sc[tid][j]);
        float l = 0.f;
        for (int j = 0; j < 32; ++j) { float p = expf(sc[tid][j] - m); sc[tid][j] = p; l += p; }
        float inv = 1.f / l;
        for (int j = 0; j < 32; ++j) sc[tid][j] *= inv;
    }
    __syncthreads();
    for (int idx = tid; idx < 16 * 72; idx += 256) {
        int i = idx / 72, d = idx - i * 72;
        float o = 0.f;
        for (int j = 0; j < 32; ++j) o += sc[i][j] * vs[j][d];
        out[((long)bn * 16 + i) * 1152 + h * 72 + d] = __float2bfloat16(o);
    }
}

// ---------------- spatial attention (qkv bf16, out bf16) ----------------
__global__ __launch_bounds__(256) void k_attn_s(
    const bf16* __restrict__ qkv, const float* __restrict__ eks,
    const float* __restrict__ evs, bf16* __restrict__ out)
{
    __shared__ float qs[64][72];
    __shared__ float ks[32][72];
    __shared__ float vs[32][72];
    __shared__ float ps[64][33];
    __shared__ float ralpha[64];
    __shared__ float rl[64];
    int blk = blockIdx.x;
    int ic = blk & 3;
    int bth = blk >> 2;
    int h = bth & 15;
    int bt = bth >> 4;
    int tid = threadIdx.x;
    int ri = tid >> 2;
    int dg = (tid & 3) * 18;
    long qkvrow0 = (long)bt * 256;
    for (int idx = tid; idx < 64 * 72; idx += 256) {
        int i = idx / 72, d = idx - i * 72;
        qs[i][d] = b2f(qkv[(qkvrow0 + ic * 64 + i) * 3456 + h * 72 + d]) * SCALE_;
    }
    float acc[18];
    #pragma unroll
    for (int e = 0; e < 18; ++e) acc[e] = 0.f;
    float m = -1e30f, l = 0.f;
    for (int jc = 0; jc < 257; jc += 32) {
        int jn = min(32, 257 - jc);
        for (int idx = tid; idx < jn * 72; idx += 256) {
            int j = idx / 72, d = idx - j * 72;
            int gj = jc + j;
            float kv, vv;
            if (gj == 0) {
                kv = eks[(long)bt * 1152 + h * 72 + d];
                vv = evs[(long)bt * 1152 + h * 72 + d];
            } else {
                long base = (qkvrow0 + gj - 1) * 3456 + h * 72 + d;
                kv = b2f(qkv[base + 1152]);
                vv = b2f(qkv[base + 2304]);
            }
            ks[j][d] = kv; vs[j][d] = vv;
        }
        __syncthreads();
        for (int e = tid; e < 64 * 32; e += 256) {
            int i = e >> 5, j = e & 31;
            float s = -1e30f;
            if (j < jn) {
                s = 0.f;
                for (int d = 0; d < 72; ++d) s += qs[i][d] * ks[j][d];
            }
            ps[i][j] = s;
        }
        __syncthreads();
        if (tid < 64) {
            float cm = m;
            for (int j = 0; j < jn; ++j) cm = fmaxf(cm, ps[tid][j]);
            float alpha = expf(m - cm);
            float sum = 0.f;
            for (int j = 0; j < jn; ++j) { float p = expf(ps[tid][j] - cm); ps[tid][j] = p; sum += p; }
            l = l * alpha + sum;
            m = cm;
            ralpha[tid] = alpha;
            rl[tid] = l;
        }
        __syncthreads();
        float alpha = ralpha[ri];
        #pragma unroll
        for (int e = 0; e < 18; ++e) acc[e] *= alpha;
        for (int j = 0; j < jn; ++j) {
            float p = ps[ri][j];
            #pragma unroll
            for (int e = 0; e < 18; ++e) acc[e] += p * vs[j][dg + e];
        }
        __syncthreads();
    }
    float invl = 1.f / rl[ri];
    long orow = qkvrow0 + ic * 64 + ri;
    #pragma unroll
    for (int e = 0; e < 18; ++e)
        out[orow * 1152 + h * 72 + dg + e] = __float2bfloat16(acc[e] * invl);
}

// ---------------- x4 = x + res (res rows are (b,n,t)) ----------------
template<int MODE>
__global__ __launch_bounds__(256) void k_add_t(
    const void* __restrict__ x, const float* __restrict__ res,
    float* __restrict__ x4, const int* __restrict__ flg)
{
    if (*flg != MODE) return;
    int idx = blockIdx.x * 256 + threadIdx.x;
    int r = idx / 1152;
    int mcol = idx - r * 1152;
    int n = r & 255;
    int bt = r >> 8;
    int b = bt >> 4, t = bt & 15;
    long r2 = (long)((b << 8) + n) * 16 + t;
    x4[idx] = ldin<MODE>(x, idx) + res[r2 * 1152 + mcol];
}

// ---------------- x4 += gate * y ; optionally emit output ----------------
template<int MODE>
__global__ __launch_bounds__(256) void k_add_g(
    float* __restrict__ x4, const float* __restrict__ y,
    const float* __restrict__ ada, int part, void* __restrict__ outp,
    const int* __restrict__ flg)
{
    if (*flg != MODE) return;
    int idx = blockIdx.x * 256 + threadIdx.x;
    int r = idx / 1152;
    int mcol = idx - r * 1152;
    int b = r >> 12;
    float g = ada[(b * 6 + part) * 1152 + mcol];
    float v = x4[idx] + g * y[idx];
    x4[idx] = v;
    if (outp) {
        if (MODE == 0) ((bf16*)outp)[idx] = __float2bfloat16(v);
        else           ((float*)outp)[idx] = v;
    }
}

extern "C" void kernel_launch(void* const* d_in, const int* in_sizes, int n_in,
                              void* d_out, int out_size, void* d_ws, size_t ws_size,
                              hipStream_t stream)
{
    const void* x      = d_in[0];
    const void* c4t    = d_in[1];
    const void* c      = d_in[2];
    const void* W_ada  = d_in[3];
    const void* b_ada  = d_in[4];
    const void* tn_w   = d_in[5];
    const void* tn_b   = d_in[6];
    const void* t_qkv  = d_in[7];
    const void* t_k    = d_in[8];
    const void* t_v    = d_in[9];
    const void* t_outw = d_in[10];
    const void* t_fcw  = d_in[11];
    const void* t_fcb  = d_in[12];
    const void* s_qkv  = d_in[13];
    const void* s_k    = d_in[14];
    const void* s_v    = d_in[15];
    const void* s_outw = d_in[16];
    const void* mlp_w1 = d_in[17];
    const void* mlp_b1 = d_in[18];
    const void* mlp_w2 = d_in[19];
    const void* mlp_b2 = d_in[20];
    const int*  f      = (const int*)d_in[21];

    float* ws    = (float*)d_ws;
    float* x4    = ws;                        //  9,437,184 f32
    float* buf2  = x4 + 9437184;              //  9,437,184 f32
    float* reg1f = buf2 + 9437184;            // 18,874,368 f32-slots (qkvb / hbf bf16)
    bf16*  qkvb  = (bf16*)reg1f;              //  8192x3456 bf16
    bf16*  hbf   = (bf16*)reg1f;              //  8192x4608 bf16
    float* abfAf = reg1f + 18874368;          //  4,718,592 f32-slots
    bf16*  abfA  = (bf16*)abfAf;
    float* abfBf = abfAf + 4718592;           //  4,718,592 f32-slots
    bf16*  abfB  = (bf16*)abfBf;
    float* wtf   = abfBf + 4718592;           // 11,280,384 f32-slots for Wt
    bf16*  wt    = (bf16*)wtf;
    bf16* t_qkv_t = wt;                        // 3,981,312
    bf16* s_qkv_t = t_qkv_t + 3981312;         // 3,981,312
    bf16* t_out_t = s_qkv_t + 3981312;         // 1,327,104
    bf16* t_fc_t  = t_out_t + 1327104;         // 1,327,104
    bf16* s_out_t = t_fc_t  + 1327104;         // 1,327,104
    bf16* w1_t    = s_out_t + 1327104;         // 5,308,416
    bf16* w2_t    = w1_t    + 5308416;         // 5,308,416
    float* small  = wtf + 11280384;
    float* ada   = small;                      // 13,824
    float* cf32  = ada  + 13824;               // 36,864
    float* ekt   = cf32 + 36864;
    float* evt   = ekt  + 36864;
    float* eks   = evt  + 36864;
    float* evs   = eks  + 36864;
    float* sc4   = evs  + 36864;               // 2,304
    float* fcb_f = sc4  + 2304;                // 1,152
    float* b1_f  = fcb_f + 1152;               // 4,608
    float* b2_f  = b1_f  + 4608;               // 1,152
    int*   flg   = (int*)(b2_f + 1152);

    k_detect<<<1, 64, 0, stream>>>(x, flg);

    // ---- modulation (parallelized): silu + tiled gemm ----
    k_silu<0><<<9, 256, 0, stream>>>(c4t, sc4, flg);
    k_silu<1><<<9, 256, 0, stream>>>(c4t, sc4, flg);
    k_gemm<0><<<dim3(108, 1), 256, 0, stream>>>(sc4, W_ada, b_ada, ada, 2, 1152, 6912, 0, flg);
    k_gemm<1><<<dim3(108, 1), 256, 0, stream>>>(sc4, W_ada, b_ada, ada, 2, 1152, 6912, 0, flg);

    // ---- context projections (tiny, f32 path) ----
    k_cvt<0><<<144, 256, 0, stream>>>(c, cf32, 36864, flg);
    k_cvt<1><<<144, 256, 0, stream>>>(c, cf32, 36864, flg);
    k_gemm<0><<<dim3(18, 1), 256, 0, stream>>>(cf32, t_k, nullptr, ekt, 32, 1152, 1152, 0, flg);
    k_gemm<1><<<dim3(18, 1), 256, 0, stream>>>(cf32, t_k, nullptr, ekt, 32, 1152, 1152, 0, flg);
    k_gemm<0><<<dim3(18, 1), 256, 0, stream>>>(cf32, t_v, nullptr, evt, 32, 1152, 1152, 0, flg);
    k_gemm<1><<<dim3(18, 1), 256, 0, stream>>>(cf32, t_v, nullptr, evt, 32, 1152, 1152, 0, flg);
    k_gemm<0><<<dim3(18, 1), 256, 0, stream>>>(cf32, s_k, nullptr, eks, 32, 1152, 1152, 0, flg);
    k_gemm<1><<<dim3(18, 1), 256, 0, stream>>>(cf32, s_k, nullptr, eks, 32, 1152, 1152, 0, flg);
    k_gemm<0><<<dim3(18, 1), 256, 0, stream>>>(cf32, s_v, nullptr, evs, 32, 1152, 1152, 0, flg);
    k_gemm<1><<<dim3(18, 1), 256, 0, stream>>>(cf32, s_v, nullptr, evs, 32, 1152, 1152, 0, flg);

    // ---- bias converts ----
    k_cvt<0><<<5, 256, 0, stream>>>(t_fcb, fcb_f, 1152, flg);
    k_cvt<1><<<5, 256, 0, stream>>>(t_fcb, fcb_f, 1152, flg);
    k_cvt<0><<<18, 256, 0, stream>>>(mlp_b1, b1_f, 4608, flg);
    k_cvt<1><<<18, 256, 0, stream>>>(mlp_b1, b1_f, 4608, flg);
    k_cvt<0><<<5, 256, 0, stream>>>(mlp_b2, b2_f, 1152, flg);
    k_cvt<1><<<5, 256, 0, stream>>>(mlp_b2, b2_f, 1152, flg);

    // ---- weight transpose+convert to NxK bf16 ----
    k_wt<0><<<dim3(108, 36), 256, 0, stream>>>(t_qkv, t_qkv_t, 1152, 3456, flg);
    k_wt<1><<<dim3(108, 36), 256, 0, stream>>>(t_qkv, t_qkv_t, 1152, 3456, flg);
    k_wt<0><<<dim3(108, 36), 256, 0, stream>>>(s_qkv, s_qkv_t, 1152, 3456, flg);
    k_wt<1><<<dim3(108, 36), 256, 0, stream>>>(s_qkv, s_qkv_t, 1152, 3456, flg);
    k_wt<0><<<dim3(36, 36), 256, 0, stream>>>(t_outw, t_out_t, 1152, 1152, flg);
    k_wt<1><<<dim3(36, 36), 256, 0, stream>>>(t_outw, t_out_t, 1152, 1152, flg);
    k_wt<0><<<dim3(36, 36), 256, 0, stream>>>(t_fcw, t_fc_t, 1152, 1152, flg);
    k_wt<1><<<dim3(36, 36), 256, 0, stream>>>(t_fcw, t_fc_t, 1152, 1152, flg);
    k_wt<0><<<dim3(36, 36), 256, 0, stream>>>(s_outw, s_out_t, 1152, 1152, flg);
    k_wt<1><<<dim3(36, 36), 256, 0, stream>>>(s_outw, s_out_t, 1152, 1152, flg);
    k_wt<0><<<dim3(144, 36), 256, 0, stream>>>(mlp_w1, w1_t, 1152, 4608, flg);
    k_wt<1><<<dim3(144, 36), 256, 0, stream>>>(mlp_w1, w1_t, 1152, 4608, flg);
    k_wt<0><<<dim3(36, 144), 256, 0, stream>>>(mlp_w2, w2_t, 4608, 1152, flg);
    k_wt<1><<<dim3(36, 144), 256, 0, stream>>>(mlp_w2, w2_t, 4608, 1152, flg);

    // ---- temporal attention ----
    k_ln_t<0><<<8192, 256, 0, stream>>>(x, tn_w, tn_b, abfA, flg);
    k_ln_t<1><<<8192, 256, 0, stream>>>(x, tn_w, tn_b, abfA, flg);
    k_mgemm<<<dim3(27, 64), 256, 0, stream>>>(abfA, t_qkv_t, nullptr, qkvb, 1152, 3456, 1, 0);
    k_attn_t<<<8192, 256, 0, stream>>>(qkvb, ekt, evt, f, abfB);
    k_mgemm<<<dim3(9, 64), 256, 0, stream>>>(abfB, t_out_t, nullptr, abfA, 1152, 1152, 1, 0);
    k_mgemm<<<dim3(9, 64), 256, 0, stream>>>(abfA, t_fc_t, fcb_f, buf2, 1152, 1152, 0, 0);
    k_add_t<0><<<36864, 256, 0, stream>>>(x, buf2, x4, flg);
    k_add_t<1><<<36864, 256, 0, stream>>>(x, buf2, x4, flg);

    // ---- spatial attention ----
    k_ln_mod<<<8192, 256, 0, stream>>>(x4, ada, 0, 1, 1e-6f, abfA);
    k_mgemm<<<dim3(27, 64), 256, 0, stream>>>(abfA, s_qkv_t, nullptr, qkvb, 1152, 3456, 1, 0);
    k_attn_s<<<2048, 256, 0, stream>>>(qkvb, eks, evs, abfB);
    k_mgemm<<<dim3(9, 64), 256, 0, stream>>>(abfB, s_out_t, nullptr, buf2, 1152, 1152, 0, 0);
    k_add_g<0><<<36864, 256, 0, stream>>>(x4, buf2, ada, 2, nullptr, flg);
    k_add_g<1><<<36864, 256, 0, stream>>>(x4, buf2, ada, 2, nullptr, flg);

    // ---- MLP ----
    k_ln_mod<<<8192, 256, 0, stream>>>(x4, ada, 3, 4, 1e-6f, abfA);
    k_mgemm<<<dim3(36, 64), 256, 0, stream>>>(abfA, w1_t, b1_f, hbf, 1152, 4608, 1, 1);
    k_mgemm<<<dim3(9, 64), 256, 0, stream>>>(hbf, w2_t, b2_f, buf2, 4608, 1152, 0, 0);
    k_add_g<0><<<36864, 256, 0, stream>>>(x4, buf2, ada, 5, d_out, flg);
    k_add_g<1><<<36864, 256, 0, stream>>>(x4, buf2, ada, 5, d_out, flg);
}

// Round 4
// 2173.413 us; speedup vs baseline: 3.9221x; 1.2260x over previous
//
#include <hip/hip_runtime.h>
#include <hip/hip_bf16.h>

typedef __hip_bfloat16 bf16;
typedef __attribute__((ext_vector_type(8))) short short8;
typedef __attribute__((ext_vector_type(4))) float floatx4;

__device__ __forceinline__ float b2f(bf16 v) { return __bfloat162float(v); }
__device__ __forceinline__ float invfreq(int jj) {
    return expf(-0.25584278811044955f * (float)jj);   // 10000^(-jj/36)
}

// MODE 0: input tensor is bf16.  MODE 1: input tensor is float32.
template<int MODE>
__device__ __forceinline__ float ldin(const void* p, long i) {
    if (MODE == 0) return b2f(((const bf16*)p)[i]);
    else           return ((const float*)p)[i];
}

#define SCALE_ 0.11785113019775793f   // 72^-0.5

// async global->LDS, 16B per lane; LDS dest is wave-uniform base + lane*16
#define GLDS(gp, lp) __builtin_amdgcn_global_load_lds( \
    (const __attribute__((address_space(1))) void*)(gp), \
    (__attribute__((address_space(3))) void*)(lp), 16, 0, 0)

// ---------------- dtype detector ----------------
__global__ void k_detect(const void* __restrict__ x, int* __restrict__ flag)
{
    const unsigned short* u = (const unsigned short*)x;
    int tid = threadIdx.x;
    int insane = 0;
    for (int i = tid; i < 2048; i += 64) {
        unsigned short s = u[i];
        int ex = (s >> 7) & 0xFF;
        if (ex >= 0xC5) insane++;
    }
    #pragma unroll
    for (int off = 32; off > 0; off >>= 1) insane += __shfl_down(insane, off);
    if (tid == 0) flag[0] = (insane > 8) ? 1 : 0;
}

// ---------------- rope cos/sin table: [t][d] for t<16, d<72 ----------------
__global__ void k_rope(const int* __restrict__ f, float* __restrict__ ropeC,
                       float* __restrict__ ropeS)
{
    int idx = blockIdx.x * 256 + threadIdx.x;
    if (idx < 1152) {
        int t = idx / 72, d = idx - t * 72;
        float ang = (float)f[t] * invfreq(d >> 1);
        float sn, cs; sincosf(ang, &sn, &cs);
        ropeC[idx] = cs;
        ropeS[idx] = sn;
    }
}

// ---------------- silu(c4t) -> f32 ----------------
template<int MODE>
__global__ void k_silu(const void* __restrict__ c4t, float* __restrict__ out,
                       const int* __restrict__ flg)
{
    if (*flg != MODE) return;
    int i = blockIdx.x * 256 + threadIdx.x;
    if (i < 2304) {
        float v = ldin<MODE>(c4t, i);
        out[i] = v / (1.f + expf(-v));
    }
}

// ---------------- input -> f32 convert/copy ----------------
template<int MODE>
__global__ void k_cvt(const void* __restrict__ in, float* __restrict__ out, int n,
                      const int* __restrict__ flg)
{
    if (*flg != MODE) return;
    int i = blockIdx.x * 256 + threadIdx.x;
    if (i < n) out[i] = ldin<MODE>(in, i);
}

// ---------------- weight transpose+convert: W (KxN, in dtype) -> Wt (NxK bf16) ----------------
template<int MODE>
__global__ __launch_bounds__(256) void k_wt(const void* __restrict__ W,
    bf16* __restrict__ Wt, int K, int N, const int* __restrict__ flg)
{
    if (*flg != MODE) return;
    __shared__ float tile[32][33];
    int n0 = blockIdx.x << 5, k0 = blockIdx.y << 5;
    int tid = threadIdx.x;
    int r = tid >> 3, c4 = (tid & 7) << 2;
    long base = (long)(k0 + r) * N + n0 + c4;
    #pragma unroll
    for (int i = 0; i < 4; ++i) tile[r][c4 + i] = ldin<MODE>(W, base + i);
    __syncthreads();
    long obase = (long)(n0 + r) * K + k0 + c4;
    #pragma unroll
    for (int i = 0; i < 4; ++i) Wt[obase + i] = __float2bfloat16(tile[c4 + i][r]);
}

// ---------------- small f32 GEMM (ada + context projections) ----------------
template<int MODE>
__global__ __launch_bounds__(256) void k_gemm(
    const float* __restrict__ A, const void* __restrict__ W,
    const void* __restrict__ bias, float* __restrict__ C,
    int R, int K, int N, int act, const int* __restrict__ flg)
{
    if (*flg != MODE) return;
    __shared__ float As[16][64];
    __shared__ float Bs[16][64];
    int tid = threadIdx.x;
    int tx = tid & 15, ty = tid >> 4;
    int row0 = blockIdx.y << 6;
    int col0 = blockIdx.x << 6;
    float acc[4][4] = {};
    int ar = tid >> 2;
    int ak = (tid & 3) << 2;
    int bk = tid >> 4;
    int bc = (tid & 15) << 2;
    for (int kt = 0; kt < K; kt += 16) {
        if (row0 + ar < R) {
            const float4 a4 = *(const float4*)(A + (long)(row0 + ar) * K + kt + ak);
            As[ak + 0][ar] = a4.x; As[ak + 1][ar] = a4.y;
            As[ak + 2][ar] = a4.z; As[ak + 3][ar] = a4.w;
        } else {
            As[ak + 0][ar] = 0.f; As[ak + 1][ar] = 0.f;
            As[ak + 2][ar] = 0.f; As[ak + 3][ar] = 0.f;
        }
        #pragma unroll
        for (int i = 0; i < 4; ++i)
            Bs[bk][bc + i] = ldin<MODE>(W, (long)(kt + bk) * N + col0 + bc + i);
        __syncthreads();
        #pragma unroll
        for (int kk = 0; kk < 16; ++kk) {
            float4 av = *(const float4*)&As[kk][ty << 2];
            float4 bv = *(const float4*)&Bs[kk][tx << 2];
            float a[4] = {av.x, av.y, av.z, av.w};
            float b[4] = {bv.x, bv.y, bv.z, bv.w};
            #pragma unroll
            for (int i = 0; i < 4; ++i)
                #pragma unroll
                for (int j = 0; j < 4; ++j)
                    acc[i][j] += a[i] * b[j];
        }
        __syncthreads();
    }
    #pragma unroll
    for (int i = 0; i < 4; ++i) {
        int gr = row0 + (ty << 2) + i;
        if (gr >= R) continue;
        float* cp = C + (long)gr * N + col0 + (tx << 2);
        #pragma unroll
        for (int j = 0; j < 4; ++j) {
            float v = acc[i][j];
            if (bias) v += ldin<MODE>(bias, col0 + (tx << 2) + j);
            cp[j] = v;
        }
    }
}

// ---------------- MFMA GEMM: A(bf16 MxK) @ Wt(bf16 NxK)^T -> C ----------------
__global__ __launch_bounds__(256) void k_mgemm(
    const bf16* __restrict__ A, const bf16* __restrict__ Wt,
    const float* __restrict__ bias, void* __restrict__ Cout,
    int K, int N, int outbf, int act)
{
    __shared__ short As[4096];
    __shared__ short Bs[4096];
    int tid = threadIdx.x;
    int lane = tid & 63, wave = tid >> 6;
    int mq = wave >> 1, nq = wave & 1;
    long row0 = (long)blockIdx.y << 7;
    long col0 = (long)blockIdx.x << 7;
    int mi = lane & 15, q = lane >> 4;

    const bf16* gA0 = A  + (row0 + (2 * wave) * 16 + mi) * K + q * 8;
    const bf16* gA1 = A  + (row0 + (2 * wave + 1) * 16 + mi) * K + q * 8;
    const bf16* gB0 = Wt + (col0 + (2 * wave) * 16 + mi) * K + q * 8;
    const bf16* gB1 = Wt + (col0 + (2 * wave + 1) * 16 + mi) * K + q * 8;
    short* lA0 = &As[(2 * wave) * 512];
    short* lA1 = &As[(2 * wave + 1) * 512];
    short* lB0 = &Bs[(2 * wave) * 512];
    short* lB1 = &Bs[(2 * wave + 1) * 512];

    floatx4 acc[4][4] = {};

    for (int kt = 0; kt < K; kt += 32) {
        GLDS(gA0 + kt, lA0);
        GLDS(gA1 + kt, lA1);
        GLDS(gB0 + kt, lB0);
        GLDS(gB1 + kt, lB1);
        __syncthreads();
        short8 af[4], bfr[4];
        #pragma unroll
        for (int i = 0; i < 4; ++i)
            af[i] = *(const short8*)&As[(4 * mq + i) * 512 + lane * 8];
        #pragma unroll
        for (int j = 0; j < 4; ++j)
            bfr[j] = *(const short8*)&Bs[(4 * nq + j) * 512 + lane * 8];
        #pragma unroll
        for (int i = 0; i < 4; ++i)
            #pragma unroll
            for (int j = 0; j < 4; ++j)
                acc[i][j] = __builtin_amdgcn_mfma_f32_16x16x32_bf16(
                    af[i], bfr[j], acc[i][j], 0, 0, 0);
        __syncthreads();
    }

    int lr = lane >> 4, lc = lane & 15;
    #pragma unroll
    for (int i = 0; i < 4; ++i) {
        #pragma unroll
        for (int r = 0; r < 4; ++r) {
            long grow = row0 + mq * 64 + i * 16 + lr * 4 + r;
            #pragma unroll
            for (int j = 0; j < 4; ++j) {
                int col = (int)col0 + nq * 64 + j * 16 + lc;
                float v = acc[i][j][r];
                if (bias) v += bias[col];
                if (act) {
                    float xx = v;
                    float inner = 0.7978845608028654f * (xx + 0.044715f * xx * xx * xx);
                    v = 0.5f * xx * (1.f + tanhf(inner));
                }
                if (outbf) ((bf16*)Cout)[grow * N + col] = __float2bfloat16(v);
                else       ((float*)Cout)[grow * N + col] = v;
            }
        }
    }
}

// ---------------- LN (temporal): x rows (b,t,n) -> bf16 rows (b,n,t) ----------------
template<int MODE>
__global__ __launch_bounds__(256) void k_ln_t(
    const void* __restrict__ x, const void* __restrict__ w,
    const void* __restrict__ bb, bf16* __restrict__ out,
    const int* __restrict__ flg)
{
    if (*flg != MODE) return;
    int r = blockIdx.x;
    int n = r & 255;
    int bt = r >> 8;
    int b = bt >> 4, t = bt & 15;
    long orow = (long)((b << 8) + n) * 16 + t;
    int tid = threadIdx.x;
    float vals[5];
    float s = 0.f, ss = 0.f;
    int c = 0;
    for (int i = tid; i < 1152; i += 256, ++c) {
        float v = ldin<MODE>(x, (long)r * 1152 + i);
        vals[c] = v; s += v; ss += v * v;
    }
    #pragma unroll
    for (int off = 32; off > 0; off >>= 1) {
        s  += __shfl_down(s, off);
        ss += __shfl_down(ss, off);
    }
    __shared__ float rs[4], rss[4];
    int wid = tid >> 6;
    if ((tid & 63) == 0) { rs[wid] = s; rss[wid] = ss; }
    __syncthreads();
    float S  = rs[0] + rs[1] + rs[2] + rs[3];
    float SS = rss[0] + rss[1] + rss[2] + rss[3];
    float mu = S * (1.f / 1152.f);
    float var = SS * (1.f / 1152.f) - mu * mu;
    float rstd = rsqrtf(var + 1e-5f);
    c = 0;
    bf16* op = out + orow * 1152;
    for (int i = tid; i < 1152; i += 256, ++c)
        op[i] = __float2bfloat16((vals[c] - mu) * rstd * ldin<MODE>(w, i) + ldin<MODE>(bb, i));
}

// ---------------- LN + adaLN modulation: x4 f32 -> bf16 ----------------
__global__ __launch_bounds__(256) void k_ln_mod(
    const float* __restrict__ x4, const float* __restrict__ ada,
    int psh, int psc, float eps, bf16* __restrict__ out)
{
    int r = blockIdx.x;
    int b = r >> 12;
    const float* xp = x4 + (long)r * 1152;
    int tid = threadIdx.x;
    float vals[5];
    float s = 0.f, ss = 0.f;
    int c = 0;
    for (int i = tid; i < 1152; i += 256, ++c) {
        float v = xp[i];
        vals[c] = v; s += v; ss += v * v;
    }
    #pragma unroll
    for (int off = 32; off > 0; off >>= 1) {
        s  += __shfl_down(s, off);
        ss += __shfl_down(ss, off);
    }
    __shared__ float rs[4], rss[4];
    int wid = tid >> 6;
    if ((tid & 63) == 0) { rs[wid] = s; rss[wid] = ss; }
    __syncthreads();
    float S  = rs[0] + rs[1] + rs[2] + rs[3];
    float SS = rss[0] + rss[1] + rss[2] + rss[3];
    float mu = S * (1.f / 1152.f);
    float var = SS * (1.f / 1152.f) - mu * mu;
    float rstd = rsqrtf(var + eps);
    const float* sh = ada + (b * 6 + psh) * 1152;
    const float* sc = ada + (b * 6 + psc) * 1152;
    c = 0;
    bf16* op = out + (long)r * 1152;
    for (int i = tid; i < 1152; i += 256, ++c)
        op[i] = __float2bfloat16((vals[c] - mu) * rstd * (1.f + sc[i]) + sh[i]);
}

// ---------------- temporal attention: conflict-free LDS, rope table ----------------
__global__ __launch_bounds__(256) void k_attn_t(
    const bf16* __restrict__ qkv, const float* __restrict__ ekt,
    const float* __restrict__ evt, const float* __restrict__ ropeC,
    const float* __restrict__ ropeS, bf16* __restrict__ out)
{
    __shared__ float qs[16][73];     // [row][d], pad 73
    __shared__ float ksT[72][33];    // TRANSPOSED: [d][key], pad 33 -> stride-1 banks
    __shared__ float vs[32][73];
    __shared__ float sc[16][33];
    int blk = blockIdx.x;
    int h = blk & 15;
    int bn = blk >> 4;
    int b = bn >> 8;
    int tid = threadIdx.x;
    long qbase = (long)bn * 16 * 3456 + h * 72;
    for (int idx = tid; idx < 16 * 72; idx += 256) {
        int i = idx / 72, d = idx - i * 72;
        long p0 = qbase + (long)i * 3456;
        float v  = b2f(qkv[p0 + d]);
        float v2 = b2f(qkv[p0 + (d ^ 1)]);
        float cs = ropeC[idx], sn = ropeS[idx];
        float rv = (d & 1) ? (v * cs + v2 * sn) : (v * cs - v2 * sn);
        qs[i][d] = rv * SCALE_;
    }
    for (int idx = tid; idx < 32 * 72; idx += 256) {
        int j = idx / 72, d = idx - j * 72;
        float kv, kv2, vv; int pi;
        if (j < 16) {
            long base = (long)(b * 16 + j) * 1152 + h * 72;
            kv  = ekt[base + d];
            kv2 = ekt[base + (d ^ 1)];
            vv  = evt[base + d];
            pi = j;
        } else {
            int jj = j - 16;
            long base = qbase + (long)jj * 3456;
            kv  = b2f(qkv[base + 1152 + d]);
            kv2 = b2f(qkv[base + 1152 + (d ^ 1)]);
            vv  = b2f(qkv[base + 2304 + d]);
            pi = jj;
        }
        float cs = ropeC[pi * 72 + d], sn = ropeS[pi * 72 + d];
        ksT[d][j] = (d & 1) ? (kv * cs + kv2 * sn) : (kv * cs - kv2 * sn);
        vs[j][d] = vv;
    }
    __syncthreads();
    for (int e = tid; e < 512; e += 256) {
        int i = e >> 5, j = e & 31;
        float s = 0.f;
        for (int d = 0; d < 72; ++d) s += qs[i][d] * ksT[d][j];
        sc[i][j] = s;
    }
    __syncthreads();
    if (tid < 16) {
        float m = -1e30f;
        for (int j = 0; j < 32; ++j) m = fmaxf(m, sc[tid][j]);
        float l = 0.f;
        for (int j = 0; j < 32; ++j) { float p = expf(sc[tid][j] - m); sc[tid][j] = p; l += p; }
        float inv = 1.f / l;
        for (int j = 0; j < 32; ++j) sc[tid][j] *= inv;
    }
    __syncthreads();
    for (int idx = tid; idx < 16 * 72; idx += 256) {
        int i = idx / 72, d = idx - i * 72;
        float o = 0.f;
        for (int j = 0; j < 32; ++j) o += sc[i][j] * vs[j][d];
        out[((long)bn * 16 + i) * 1152 + h * 72 + d] = __float2bfloat16(o);
    }
}

// ---------------- spatial attention: conflict-free LDS, 4x2 register tile ----------------
__global__ __launch_bounds__(256) void k_attn_s(
    const bf16* __restrict__ qkv, const float* __restrict__ eks,
    const float* __restrict__ evs, bf16* __restrict__ out)
{
    __shared__ float qs[64][73];     // pad 73
    __shared__ float ksT[72][33];    // TRANSPOSED [d][key]
    __shared__ float vs[32][73];
    __shared__ float ps[64][33];
    __shared__ float ralpha[64];
    __shared__ float rl[64];
    int blk = blockIdx.x;
    int ic = blk & 3;
    int bth = blk >> 2;
    int h = bth & 15;
    int bt = bth >> 4;
    int tid = threadIdx.x;
    int rg = tid >> 4;               // QK: 4-row group
    int cg = tid & 15;               // QK: 2-col group
    int ri = tid >> 2;               // PV: row
    int dg = (tid & 3) * 18;         // PV: d-group
    long qkvrow0 = (long)bt * 256;
    for (int idx = tid; idx < 64 * 72; idx += 256) {
        int i = idx / 72, d = idx - i * 72;
        qs[i][d] = b2f(qkv[(qkvrow0 + ic * 64 + i) * 3456 + h * 72 + d]) * SCALE_;
    }
    float acc[18];
    #pragma unroll
    for (int e = 0; e < 18; ++e) acc[e] = 0.f;
    float m = -1e30f, l = 0.f;
    for (int jc = 0; jc < 257; jc += 32) {
        int jn = min(32, 257 - jc);
        for (int idx = tid; idx < jn * 72; idx += 256) {
            int j = idx / 72, d = idx - j * 72;
            int gj = jc + j;
            float kv, vv;
            if (gj == 0) {
                kv = eks[(long)bt * 1152 + h * 72 + d];
                vv = evs[(long)bt * 1152 + h * 72 + d];
            } else {
                long base = (qkvrow0 + gj - 1) * 3456 + h * 72 + d;
                kv = b2f(qkv[base + 1152]);
                vv = b2f(qkv[base + 2304]);
            }
            ksT[d][j] = kv; vs[j][d] = vv;
        }
        __syncthreads();
        // QK: each thread computes 4 rows x 2 cols
        {
            float s00 = 0.f, s01 = 0.f, s10 = 0.f, s11 = 0.f;
            float s20 = 0.f, s21 = 0.f, s30 = 0.f, s31 = 0.f;
            const float* q0 = qs[rg * 4 + 0];
            const float* q1 = qs[rg * 4 + 1];
            const float* q2 = qs[rg * 4 + 2];
            const float* q3 = qs[rg * 4 + 3];
            const int c0 = cg * 2, c1 = cg * 2 + 1;
            for (int d = 0; d < 72; ++d) {
                float k0 = ksT[d][c0], k1 = ksT[d][c1];
                float a0 = q0[d], a1 = q1[d], a2 = q2[d], a3 = q3[d];
                s00 += a0 * k0; s01 += a0 * k1;
                s10 += a1 * k0; s11 += a1 * k1;
                s20 += a2 * k0; s21 += a2 * k1;
                s30 += a3 * k0; s31 += a3 * k1;
            }
            ps[rg * 4 + 0][c0] = s00; ps[rg * 4 + 0][c1] = s01;
            ps[rg * 4 + 1][c0] = s10; ps[rg * 4 + 1][c1] = s11;
            ps[rg * 4 + 2][c0] = s20; ps[rg * 4 + 2][c1] = s21;
            ps[rg * 4 + 3][c0] = s30; ps[rg * 4 + 3][c1] = s31;
        }
        __syncthreads();
        if (tid < 64) {
            float cm = m;
            for (int j = 0; j < jn; ++j) cm = fmaxf(cm, ps[tid][j]);
            float alpha = expf(m - cm);
            float sum = 0.f;
            for (int j = 0; j < jn; ++j) { float p = expf(ps[tid][j] - cm); ps[tid][j] = p; sum += p; }
            l = l * alpha + sum;
            m = cm;
            ralpha[tid] = alpha;
            rl[tid] = l;
        }
        __syncthreads();
        float alpha = ralpha[ri];
        #pragma unroll
        for (int e = 0; e < 18; ++e) acc[e] *= alpha;
        for (int j = 0; j < jn; ++j) {
            float p = ps[ri][j];
            #pragma unroll
            for (int e = 0; e < 18; ++e) acc[e] += p * vs[j][dg + e];
        }
        __syncthreads();
    }
    float invl = 1.f / rl[ri];
    long orow = qkvrow0 + ic * 64 + ri;
    #pragma unroll
    for (int e = 0; e < 18; ++e)
        out[orow * 1152 + h * 72 + dg + e] = __float2bfloat16(acc[e] * invl);
}

// ---------------- x4 = x + res (res rows are (b,n,t)) ----------------
template<int MODE>
__global__ __launch_bounds__(256) void k_add_t(
    const void* __restrict__ x, const float* __restrict__ res,
    float* __restrict__ x4, const int* __restrict__ flg)
{
    if (*flg != MODE) return;
    int idx = blockIdx.x * 256 + threadIdx.x;
    int r = idx / 1152;
    int mcol = idx - r * 1152;
    int n = r & 255;
    int bt = r >> 8;
    int b = bt >> 4, t = bt & 15;
    long r2 = (long)((b << 8) + n) * 16 + t;
    x4[idx] = ldin<MODE>(x, idx) + res[r2 * 1152 + mcol];
}

// ---------------- x4 += gate * y ; optionally emit output ----------------
template<int MODE>
__global__ __launch_bounds__(256) void k_add_g(
    float* __restrict__ x4, const float* __restrict__ y,
    const float* __restrict__ ada, int part, void* __restrict__ outp,
    const int* __restrict__ flg)
{
    if (*flg != MODE) return;
    int idx = blockIdx.x * 256 + threadIdx.x;
    int r = idx / 1152;
    int mcol = idx - r * 1152;
    int b = r >> 12;
    float g = ada[(b * 6 + part) * 1152 + mcol];
    float v = x4[idx] + g * y[idx];
    x4[idx] = v;
    if (outp) {
        if (MODE == 0) ((bf16*)outp)[idx] = __float2bfloat16(v);
        else           ((float*)outp)[idx] = v;
    }
}

extern "C" void kernel_launch(void* const* d_in, const int* in_sizes, int n_in,
                              void* d_out, int out_size, void* d_ws, size_t ws_size,
                              hipStream_t stream)
{
    const void* x      = d_in[0];
    const void* c4t    = d_in[1];
    const void* c      = d_in[2];
    const void* W_ada  = d_in[3];
    const void* b_ada  = d_in[4];
    const void* tn_w   = d_in[5];
    const void* tn_b   = d_in[6];
    const void* t_qkv  = d_in[7];
    const void* t_k    = d_in[8];
    const void* t_v    = d_in[9];
    const void* t_outw = d_in[10];
    const void* t_fcw  = d_in[11];
    const void* t_fcb  = d_in[12];
    const void* s_qkv  = d_in[13];
    const void* s_k    = d_in[14];
    const void* s_v    = d_in[15];
    const void* s_outw = d_in[16];
    const void* mlp_w1 = d_in[17];
    const void* mlp_b1 = d_in[18];
    const void* mlp_w2 = d_in[19];
    const void* mlp_b2 = d_in[20];
    const int*  f      = (const int*)d_in[21];

    float* ws    = (float*)d_ws;
    float* x4    = ws;                        //  9,437,184 f32
    float* buf2  = x4 + 9437184;              //  9,437,184 f32
    float* reg1f = buf2 + 9437184;            // 18,874,368 f32-slots (qkvb / hbf bf16)
    bf16*  qkvb  = (bf16*)reg1f;
    bf16*  hbf   = (bf16*)reg1f;
    float* abfAf = reg1f + 18874368;          //  4,718,592 f32-slots
    bf16*  abfA  = (bf16*)abfAf;
    float* abfBf = abfAf + 4718592;           //  4,718,592 f32-slots
    bf16*  abfB  = (bf16*)abfBf;
    float* wtf   = abfBf + 4718592;           // 11,280,384 f32-slots for Wt
    bf16*  wt    = (bf16*)wtf;
    bf16* t_qkv_t = wt;                        // 3,981,312
    bf16* s_qkv_t = t_qkv_t + 3981312;         // 3,981,312
    bf16* t_out_t = s_qkv_t + 3981312;         // 1,327,104
    bf16* t_fc_t  = t_out_t + 1327104;         // 1,327,104
    bf16* s_out_t = t_fc_t  + 1327104;         // 1,327,104
    bf16* w1_t    = s_out_t + 1327104;         // 5,308,416
    bf16* w2_t    = w1_t    + 5308416;         // 5,308,416
    float* small  = wtf + 11280384;
    float* ada   = small;                      // 13,824
    float* cf32  = ada  + 13824;               // 36,864
    float* ekt   = cf32 + 36864;
    float* evt   = ekt  + 36864;
    float* eks   = evt  + 36864;
    float* evs   = eks  + 36864;
    float* sc4   = evs  + 36864;               // 2,304
    float* fcb_f = sc4  + 2304;                // 1,152
    float* b1_f  = fcb_f + 1152;               // 4,608
    float* b2_f  = b1_f  + 4608;               // 1,152
    float* ropeC = b2_f + 1152;                // 1,152
    float* ropeS = ropeC + 1152;               // 1,152
    int*   flg   = (int*)(ropeS + 1152);

    k_detect<<<1, 64, 0, stream>>>(x, flg);
    k_rope<<<5, 256, 0, stream>>>(f, ropeC, ropeS);

    // ---- modulation: silu + tiled gemm ----
    k_silu<0><<<9, 256, 0, stream>>>(c4t, sc4, flg);
    k_silu<1><<<9, 256, 0, stream>>>(c4t, sc4, flg);
    k_gemm<0><<<dim3(108, 1), 256, 0, stream>>>(sc4, W_ada, b_ada, ada, 2, 1152, 6912, 0, flg);
    k_gemm<1><<<dim3(108, 1), 256, 0, stream>>>(sc4, W_ada, b_ada, ada, 2, 1152, 6912, 0, flg);

    // ---- context projections ----
    k_cvt<0><<<144, 256, 0, stream>>>(c, cf32, 36864, flg);
    k_cvt<1><<<144, 256, 0, stream>>>(c, cf32, 36864, flg);
    k_gemm<0><<<dim3(18, 1), 256, 0, stream>>>(cf32, t_k, nullptr, ekt, 32, 1152, 1152, 0, flg);
    k_gemm<1><<<dim3(18, 1), 256, 0, stream>>>(cf32, t_k, nullptr, ekt, 32, 1152, 1152, 0, flg);
    k_gemm<0><<<dim3(18, 1), 256, 0, stream>>>(cf32, t_v, nullptr, evt, 32, 1152, 1152, 0, flg);
    k_gemm<1><<<dim3(18, 1), 256, 0, stream>>>(cf32, t_v, nullptr, evt, 32, 1152, 1152, 0, flg);
    k_gemm<0><<<dim3(18, 1), 256, 0, stream>>>(cf32, s_k, nullptr, eks, 32, 1152, 1152, 0, flg);
    k_gemm<1><<<dim3(18, 1), 256, 0, stream>>>(cf32, s_k, nullptr, eks, 32, 1152, 1152, 0, flg);
    k_gemm<0><<<dim3(18, 1), 256, 0, stream>>>(cf32, s_v, nullptr, evs, 32, 1152, 1152, 0, flg);
    k_gemm<1><<<dim3(18, 1), 256, 0, stream>>>(cf32, s_v, nullptr, evs, 32, 1152, 1152, 0, flg);

    // ---- bias converts ----
    k_cvt<0><<<5, 256, 0, stream>>>(t_fcb, fcb_f, 1152, flg);
    k_cvt<1><<<5, 256, 0, stream>>>(t_fcb, fcb_f, 1152, flg);
    k_cvt<0><<<18, 256, 0, stream>>>(mlp_b1, b1_f, 4608, flg);
    k_cvt<1><<<18, 256, 0, stream>>>(mlp_b1, b1_f, 4608, flg);
    k_cvt<0><<<5, 256, 0, stream>>>(mlp_b2, b2_f, 1152, flg);
    k_cvt<1><<<5, 256, 0, stream>>>(mlp_b2, b2_f, 1152, flg);

    // ---- weight transpose+convert to NxK bf16 ----
    k_wt<0><<<dim3(108, 36), 256, 0, stream>>>(t_qkv, t_qkv_t, 1152, 3456, flg);
    k_wt<1><<<dim3(108, 36), 256, 0, stream>>>(t_qkv, t_qkv_t, 1152, 3456, flg);
    k_wt<0><<<dim3(108, 36), 256, 0, stream>>>(s_qkv, s_qkv_t, 1152, 3456, flg);
    k_wt<1><<<dim3(108, 36), 256, 0, stream>>>(s_qkv, s_qkv_t, 1152, 3456, flg);
    k_wt<0><<<dim3(36, 36), 256, 0, stream>>>(t_outw, t_out_t, 1152, 1152, flg);
    k_wt<1><<<dim3(36, 36), 256, 0, stream>>>(t_outw, t_out_t, 1152, 1152, flg);
    k_wt<0><<<dim3(36, 36), 256, 0, stream>>>(t_fcw, t_fc_t, 1152, 1152, flg);
    k_wt<1><<<dim3(36, 36), 256, 0, stream>>>(t_fcw, t_fc_t, 1152, 1152, flg);
    k_wt<0><<<dim3(36, 36), 256, 0, stream>>>(s_outw, s_out_t, 1152, 1152, flg);
    k_wt<1><<<dim3(36, 36), 256, 0, stream>>>(s_outw, s_out_t, 1152, 1152, flg);
    k_wt<0><<<dim3(144, 36), 256, 0, stream>>>(mlp_w1, w1_t, 1152, 4608, flg);
    k_wt<1><<<dim3(144, 36), 256, 0, stream>>>(mlp_w1, w1_t, 1152, 4608, flg);
    k_wt<0><<<dim3(36, 144), 256, 0, stream>>>(mlp_w2, w2_t, 4608, 1152, flg);
    k_wt<1><<<dim3(36, 144), 256, 0, stream>>>(mlp_w2, w2_t, 4608, 1152, flg);

    // ---- temporal attention ----
    k_ln_t<0><<<8192, 256, 0, stream>>>(x, tn_w, tn_b, abfA, flg);
    k_ln_t<1><<<8192, 256, 0, stream>>>(x, tn_w, tn_b, abfA, flg);
    k_mgemm<<<dim3(27, 64), 256, 0, stream>>>(abfA, t_qkv_t, nullptr, qkvb, 1152, 3456, 1, 0);
    k_attn_t<<<8192, 256, 0, stream>>>(qkvb, ekt, evt, ropeC, ropeS, abfB);
    k_mgemm<<<dim3(9, 64), 256, 0, stream>>>(abfB, t_out_t, nullptr, abfA, 1152, 1152, 1, 0);
    k_mgemm<<<dim3(9, 64), 256, 0, stream>>>(abfA, t_fc_t, fcb_f, buf2, 1152, 1152, 0, 0);
    k_add_t<0><<<36864, 256, 0, stream>>>(x, buf2, x4, flg);
    k_add_t<1><<<36864, 256, 0, stream>>>(x, buf2, x4, flg);

    // ---- spatial attention ----
    k_ln_mod<<<8192, 256, 0, stream>>>(x4, ada, 0, 1, 1e-6f, abfA);
    k_mgemm<<<dim3(27, 64), 256, 0, stream>>>(abfA, s_qkv_t, nullptr, qkvb, 1152, 3456, 1, 0);
    k_attn_s<<<2048, 256, 0, stream>>>(qkvb, eks, evs, abfB);
    k_mgemm<<<dim3(9, 64), 256, 0, stream>>>(abfB, s_out_t, nullptr, buf2, 1152, 1152, 0, 0);
    k_add_g<0><<<36864, 256, 0, stream>>>(x4, buf2, ada, 2, nullptr, flg);
    k_add_g<1><<<36864, 256, 0, stream>>>(x4, buf2, ada, 2, nullptr, flg);

    // ---- MLP ----
    k_ln_mod<<<8192, 256, 0, stream>>>(x4, ada, 3, 4, 1e-6f, abfA);
    k_mgemm<<<dim3(36, 64), 256, 0, stream>>>(abfA, w1_t, b1_f, hbf, 1152, 4608, 1, 1);
    k_mgemm<<<dim3(9, 64), 256, 0, stream>>>(hbf, w2_t, b2_f, buf2, 4608, 1152, 0, 0);
    k_add_g<0><<<36864, 256, 0, stream>>>(x4, buf2, ada, 5, d_out, flg);
    k_add_g<1><<<36864, 256, 0, stream>>>(x4, buf2, ada, 5, d_out, flg);
}

// Round 5
// 1899.056 us; speedup vs baseline: 4.4888x; 1.1445x over previous
//
#include <hip/hip_runtime.h>
#include <hip/hip_bf16.h>

typedef __hip_bfloat16 bf16;
typedef __attribute__((ext_vector_type(8))) short short8;
typedef __attribute__((ext_vector_type(4))) float floatx4;

__device__ __forceinline__ float b2f(bf16 v) { return __bfloat162float(v); }
__device__ __forceinline__ short f2bs(float v) {
    bf16 h = __float2bfloat16(v);
    return *(short*)&h;
}
__device__ __forceinline__ float invfreq(int jj) {
    return expf(-0.25584278811044955f * (float)jj);   // 10000^(-jj/36)
}

// MODE 0: input tensor is bf16.  MODE 1: input tensor is float32.
template<int MODE>
__device__ __forceinline__ float ldin(const void* p, long i) {
    if (MODE == 0) return b2f(((const bf16*)p)[i]);
    else           return ((const float*)p)[i];
}

#define SCALE_ 0.11785113019775793f   // 72^-0.5

// async global->LDS, 16B per lane
#define GLDS(gp, lp) __builtin_amdgcn_global_load_lds( \
    (const __attribute__((address_space(1))) void*)(gp), \
    (__attribute__((address_space(3))) void*)(lp), 16, 0, 0)

// ---------------- dtype detector ----------------
__global__ void k_detect(const void* __restrict__ x, int* __restrict__ flag)
{
    const unsigned short* u = (const unsigned short*)x;
    int tid = threadIdx.x;
    int insane = 0;
    for (int i = tid; i < 2048; i += 64) {
        unsigned short s = u[i];
        int ex = (s >> 7) & 0xFF;
        if (ex >= 0xC5) insane++;
    }
    #pragma unroll
    for (int off = 32; off > 0; off >>= 1) insane += __shfl_down(insane, off);
    if (tid == 0) flag[0] = (insane > 8) ? 1 : 0;
}

// ---------------- rope cos/sin table ----------------
__global__ void k_rope(const int* __restrict__ f, float* __restrict__ ropeC,
                       float* __restrict__ ropeS)
{
    int idx = blockIdx.x * 256 + threadIdx.x;
    if (idx < 1152) {
        int t = idx / 72, d = idx - t * 72;
        float ang = (float)f[t] * invfreq(d >> 1);
        float sn, cs; sincosf(ang, &sn, &cs);
        ropeC[idx] = cs;
        ropeS[idx] = sn;
    }
}

// ---------------- silu(c4t) -> f32 ----------------
template<int MODE>
__global__ void k_silu(const void* __restrict__ c4t, float* __restrict__ out,
                       const int* __restrict__ flg)
{
    if (*flg != MODE) return;
    int i = blockIdx.x * 256 + threadIdx.x;
    if (i < 2304) {
        float v = ldin<MODE>(c4t, i);
        out[i] = v / (1.f + expf(-v));
    }
}

// ---------------- input -> f32 convert/copy ----------------
template<int MODE>
__global__ void k_cvt(const void* __restrict__ in, float* __restrict__ out, int n,
                      const int* __restrict__ flg)
{
    if (*flg != MODE) return;
    int i = blockIdx.x * 256 + threadIdx.x;
    if (i < n) out[i] = ldin<MODE>(in, i);
}

// ---------------- f32 -> bf16 convert ----------------
__global__ void k_cvtb(const float* __restrict__ in, bf16* __restrict__ out, int n)
{
    int i = blockIdx.x * 256 + threadIdx.x;
    if (i < n) out[i] = __float2bfloat16(in[i]);
}

// ---------------- weight transpose+convert: W (KxN) -> Wt (NxK bf16) ----------------
template<int MODE>
__global__ __launch_bounds__(256) void k_wt(const void* __restrict__ W,
    bf16* __restrict__ Wt, int K, int N, const int* __restrict__ flg)
{
    if (*flg != MODE) return;
    __shared__ float tile[32][33];
    int n0 = blockIdx.x << 5, k0 = blockIdx.y << 5;
    int tid = threadIdx.x;
    int r = tid >> 3, c4 = (tid & 7) << 2;
    long base = (long)(k0 + r) * N + n0 + c4;
    #pragma unroll
    for (int i = 0; i < 4; ++i) tile[r][c4 + i] = ldin<MODE>(W, base + i);
    __syncthreads();
    long obase = (long)(n0 + r) * K + k0 + c4;
    #pragma unroll
    for (int i = 0; i < 4; ++i) Wt[obase + i] = __float2bfloat16(tile[c4 + i][r]);
}

// ---------------- small f32 GEMM (ada + context projections) ----------------
template<int MODE>
__global__ __launch_bounds__(256) void k_gemm(
    const float* __restrict__ A, const void* __restrict__ W,
    const void* __restrict__ bias, float* __restrict__ C,
    int R, int K, int N, int act, const int* __restrict__ flg)
{
    if (*flg != MODE) return;
    __shared__ float As[16][64];
    __shared__ float Bs[16][64];
    int tid = threadIdx.x;
    int tx = tid & 15, ty = tid >> 4;
    int row0 = blockIdx.y << 6;
    int col0 = blockIdx.x << 6;
    float acc[4][4] = {};
    int ar = tid >> 2;
    int ak = (tid & 3) << 2;
    int bk = tid >> 4;
    int bc = (tid & 15) << 2;
    for (int kt = 0; kt < K; kt += 16) {
        if (row0 + ar < R) {
            const float4 a4 = *(const float4*)(A + (long)(row0 + ar) * K + kt + ak);
            As[ak + 0][ar] = a4.x; As[ak + 1][ar] = a4.y;
            As[ak + 2][ar] = a4.z; As[ak + 3][ar] = a4.w;
        } else {
            As[ak + 0][ar] = 0.f; As[ak + 1][ar] = 0.f;
            As[ak + 2][ar] = 0.f; As[ak + 3][ar] = 0.f;
        }
        #pragma unroll
        for (int i = 0; i < 4; ++i)
            Bs[bk][bc + i] = ldin<MODE>(W, (long)(kt + bk) * N + col0 + bc + i);
        __syncthreads();
        #pragma unroll
        for (int kk = 0; kk < 16; ++kk) {
            float4 av = *(const float4*)&As[kk][ty << 2];
            float4 bv = *(const float4*)&Bs[kk][tx << 2];
            float a[4] = {av.x, av.y, av.z, av.w};
            float b[4] = {bv.x, bv.y, bv.z, bv.w};
            #pragma unroll
            for (int i = 0; i < 4; ++i)
                #pragma unroll
                for (int j = 0; j < 4; ++j)
                    acc[i][j] += a[i] * b[j];
        }
        __syncthreads();
    }
    #pragma unroll
    for (int i = 0; i < 4; ++i) {
        int gr = row0 + (ty << 2) + i;
        if (gr >= R) continue;
        float* cp = C + (long)gr * N + col0 + (tx << 2);
        #pragma unroll
        for (int j = 0; j < 4; ++j) {
            float v = acc[i][j];
            if (bias) v += ldin<MODE>(bias, col0 + (tx << 2) + j);
            cp[j] = v;
        }
    }
}

// ---------------- MFMA GEMM: A(bf16 MxK) @ Wt(bf16 NxK)^T -> C ----------------
__global__ __launch_bounds__(256) void k_mgemm(
    const bf16* __restrict__ A, const bf16* __restrict__ Wt,
    const float* __restrict__ bias, void* __restrict__ Cout,
    int K, int N, int outbf, int act)
{
    __shared__ short As[4096];
    __shared__ short Bs[4096];
    int tid = threadIdx.x;
    int lane = tid & 63, wave = tid >> 6;
    int mq = wave >> 1, nq = wave & 1;
    long row0 = (long)blockIdx.y << 7;
    long col0 = (long)blockIdx.x << 7;
    int mi = lane & 15, q = lane >> 4;

    const bf16* gA0 = A  + (row0 + (2 * wave) * 16 + mi) * K + q * 8;
    const bf16* gA1 = A  + (row0 + (2 * wave + 1) * 16 + mi) * K + q * 8;
    const bf16* gB0 = Wt + (col0 + (2 * wave) * 16 + mi) * K + q * 8;
    const bf16* gB1 = Wt + (col0 + (2 * wave + 1) * 16 + mi) * K + q * 8;
    short* lA0 = &As[(2 * wave) * 512];
    short* lA1 = &As[(2 * wave + 1) * 512];
    short* lB0 = &Bs[(2 * wave) * 512];
    short* lB1 = &Bs[(2 * wave + 1) * 512];

    floatx4 acc[4][4] = {};

    for (int kt = 0; kt < K; kt += 32) {
        GLDS(gA0 + kt, lA0);
        GLDS(gA1 + kt, lA1);
        GLDS(gB0 + kt, lB0);
        GLDS(gB1 + kt, lB1);
        __syncthreads();
        short8 af[4], bfr[4];
        #pragma unroll
        for (int i = 0; i < 4; ++i)
            af[i] = *(const short8*)&As[(4 * mq + i) * 512 + lane * 8];
        #pragma unroll
        for (int j = 0; j < 4; ++j)
            bfr[j] = *(const short8*)&Bs[(4 * nq + j) * 512 + lane * 8];
        #pragma unroll
        for (int i = 0; i < 4; ++i)
            #pragma unroll
            for (int j = 0; j < 4; ++j)
                acc[i][j] = __builtin_amdgcn_mfma_f32_16x16x32_bf16(
                    af[i], bfr[j], acc[i][j], 0, 0, 0);
        __syncthreads();
    }

    int lr = lane >> 4, lc = lane & 15;
    #pragma unroll
    for (int i = 0; i < 4; ++i) {
        #pragma unroll
        for (int r = 0; r < 4; ++r) {
            long grow = row0 + mq * 64 + i * 16 + lr * 4 + r;
            #pragma unroll
            for (int j = 0; j < 4; ++j) {
                int col = (int)col0 + nq * 64 + j * 16 + lc;
                float v = acc[i][j][r];
                if (bias) v += bias[col];
                if (act) {
                    float xx = v;
                    float inner = 0.7978845608028654f * (xx + 0.044715f * xx * xx * xx);
                    v = 0.5f * xx * (1.f + tanhf(inner));
                }
                if (outbf) ((bf16*)Cout)[grow * N + col] = __float2bfloat16(v);
                else       ((float*)Cout)[grow * N + col] = v;
            }
        }
    }
}

// ---------------- LN (temporal) ----------------
template<int MODE>
__global__ __launch_bounds__(256) void k_ln_t(
    const void* __restrict__ x, const void* __restrict__ w,
    const void* __restrict__ bb, bf16* __restrict__ out,
    const int* __restrict__ flg)
{
    if (*flg != MODE) return;
    int r = blockIdx.x;
    int n = r & 255;
    int bt = r >> 8;
    int b = bt >> 4, t = bt & 15;
    long orow = (long)((b << 8) + n) * 16 + t;
    int tid = threadIdx.x;
    float vals[5];
    float s = 0.f, ss = 0.f;
    int c = 0;
    for (int i = tid; i < 1152; i += 256, ++c) {
        float v = ldin<MODE>(x, (long)r * 1152 + i);
        vals[c] = v; s += v; ss += v * v;
    }
    #pragma unroll
    for (int off = 32; off > 0; off >>= 1) {
        s  += __shfl_down(s, off);
        ss += __shfl_down(ss, off);
    }
    __shared__ float rs[4], rss[4];
    int wid = tid >> 6;
    if ((tid & 63) == 0) { rs[wid] = s; rss[wid] = ss; }
    __syncthreads();
    float S  = rs[0] + rs[1] + rs[2] + rs[3];
    float SS = rss[0] + rss[1] + rss[2] + rss[3];
    float mu = S * (1.f / 1152.f);
    float var = SS * (1.f / 1152.f) - mu * mu;
    float rstd = rsqrtf(var + 1e-5f);
    c = 0;
    bf16* op = out + orow * 1152;
    for (int i = tid; i < 1152; i += 256, ++c)
        op[i] = __float2bfloat16((vals[c] - mu) * rstd * ldin<MODE>(w, i) + ldin<MODE>(bb, i));
}

// ---------------- LN + adaLN modulation ----------------
__global__ __launch_bounds__(256) void k_ln_mod(
    const float* __restrict__ x4, const float* __restrict__ ada,
    int psh, int psc, float eps, bf16* __restrict__ out)
{
    int r = blockIdx.x;
    int b = r >> 12;
    const float* xp = x4 + (long)r * 1152;
    int tid = threadIdx.x;
    float vals[5];
    float s = 0.f, ss = 0.f;
    int c = 0;
    for (int i = tid; i < 1152; i += 256, ++c) {
        float v = xp[i];
        vals[c] = v; s += v; ss += v * v;
    }
    #pragma unroll
    for (int off = 32; off > 0; off >>= 1) {
        s  += __shfl_down(s, off);
        ss += __shfl_down(ss, off);
    }
    __shared__ float rs[4], rss[4];
    int wid = tid >> 6;
    if ((tid & 63) == 0) { rs[wid] = s; rss[wid] = ss; }
    __syncthreads();
    float S  = rs[0] + rs[1] + rs[2] + rs[3];
    float SS = rss[0] + rss[1] + rss[2] + rss[3];
    float mu = S * (1.f / 1152.f);
    float var = SS * (1.f / 1152.f) - mu * mu;
    float rstd = rsqrtf(var + eps);
    const float* sh = ada + (b * 6 + psh) * 1152;
    const float* sc = ada + (b * 6 + psc) * 1152;
    c = 0;
    bf16* op = out + (long)r * 1152;
    for (int i = tid; i < 1152; i += 256, ++c)
        op[i] = __float2bfloat16((vals[c] - mu) * rstd * (1.f + sc[i]) + sh[i]);
}

// ---------------- temporal attention (unchanged: conflict-free VALU) ----------------
__global__ __launch_bounds__(256) void k_attn_t(
    const bf16* __restrict__ qkv, const float* __restrict__ ekt,
    const float* __restrict__ evt, const float* __restrict__ ropeC,
    const float* __restrict__ ropeS, bf16* __restrict__ out)
{
    __shared__ float qs[16][73];
    __shared__ float ksT[72][33];
    __shared__ float vs[32][73];
    __shared__ float sc[16][33];
    int blk = blockIdx.x;
    int h = blk & 15;
    int bn = blk >> 4;
    int b = bn >> 8;
    int tid = threadIdx.x;
    long qbase = (long)bn * 16 * 3456 + h * 72;
    for (int idx = tid; idx < 16 * 72; idx += 256) {
        int i = idx / 72, d = idx - i * 72;
        long p0 = qbase + (long)i * 3456;
        float v  = b2f(qkv[p0 + d]);
        float v2 = b2f(qkv[p0 + (d ^ 1)]);
        float cs = ropeC[idx], sn = ropeS[idx];
        float rv = (d & 1) ? (v * cs + v2 * sn) : (v * cs - v2 * sn);
        qs[i][d] = rv * SCALE_;
    }
    for (int idx = tid; idx < 32 * 72; idx += 256) {
        int j = idx / 72, d = idx - j * 72;
        float kv, kv2, vv; int pi;
        if (j < 16) {
            long base = (long)(b * 16 + j) * 1152 + h * 72;
            kv  = ekt[base + d];
            kv2 = ekt[base + (d ^ 1)];
            vv  = evt[base + d];
            pi = j;
        } else {
            int jj = j - 16;
            long base = qbase + (long)jj * 3456;
            kv  = b2f(qkv[base + 1152 + d]);
            kv2 = b2f(qkv[base + 1152 + (d ^ 1)]);
            vv  = b2f(qkv[base + 2304 + d]);
            pi = jj;
        }
        float cs = ropeC[pi * 72 + d], sn = ropeS[pi * 72 + d];
        ksT[d][j] = (d & 1) ? (kv * cs + kv2 * sn) : (kv * cs - kv2 * sn);
        vs[j][d] = vv;
    }
    __syncthreads();
    for (int e = tid; e < 512; e += 256) {
        int i = e >> 5, j = e & 31;
        float s = 0.f;
        for (int d = 0; d < 72; ++d) s += qs[i][d] * ksT[d][j];
        sc[i][j] = s;
    }
    __syncthreads();
    if (tid < 16) {
        float m = -1e30f;
        for (int j = 0; j < 32; ++j) m = fmaxf(m, sc[tid][j]);
        float l = 0.f;
        for (int j = 0; j < 32; ++j) { float p = expf(sc[tid][j] - m); sc[tid][j] = p; l += p; }
        float inv = 1.f / l;
        for (int j = 0; j < 32; ++j) sc[tid][j] *= inv;
    }
    __syncthreads();
    for (int idx = tid; idx < 16 * 72; idx += 256) {
        int i = idx / 72, d = idx - i * 72;
        float o = 0.f;
        for (int j = 0; j < 32; ++j) o += sc[i][j] * vs[j][d];
        out[((long)bn * 16 + i) * 1152 + h * 72 + d] = __float2bfloat16(o);
    }
}

// ---------------- spatial attention: MFMA flash ----------------
// block = (b,t,h,quarter): 4 waves, each one 16-row m-tile. Keys 0..256
// (0=context). K-dim 72 padded to 96 via zeroed frags.
__global__ __launch_bounds__(256) void k_attn_s(
    const bf16* __restrict__ qkv, const bf16* __restrict__ eksb,
    const bf16* __restrict__ evsb, bf16* __restrict__ out)
{
    __shared__ short vT[5120];       // V^T frag-linear: (dn*2+ks)*512 + fl*8
    __shared__ short pl[4][1024];    // per-wave P frags: ks*512 + lane*8
    int tid = threadIdx.x;
    int lane = tid & 63, wave = tid >> 6;
    int blk = blockIdx.x;
    int ic = blk & 3;
    int bth = blk >> 2;
    int h = bth & 15;
    int bt = bth >> 4;
    int col = lane & 15, q = lane >> 4;
    int hoff = h * 72;
    long qkvbase = (long)bt * 256 * 3456;
    long ctxbase = (long)bt * 1152 + hoff;

    // Q fragments (A-operand), rows = ic*64 + wave*16 + (lane&15)
    int qrow = ic * 64 + wave * 16 + col;
    const bf16* qptr = qkv + qkvbase + (long)qrow * 3456 + hoff;
    short8 qf[3];
    #pragma unroll
    for (int ks = 0; ks < 3; ++ks) {
        int k0 = ks * 32 + q * 8;
        if (k0 + 8 <= 72) qf[ks] = *(const short8*)(qptr + k0);
        else { short8 z = {0,0,0,0,0,0,0,0}; qf[ks] = z; }
    }

    floatx4 o[5] = {};
    float m_i[4], l_i[4];
    #pragma unroll
    for (int r = 0; r < 4; ++r) { m_i[r] = -1e30f; l_i[r] = 0.f; }

    for (int kc = 0; kc < 320; kc += 64) {
        // ---- stage V^T chunk (frag-linear) ----
        for (int fi = tid; fi < 640; fi += 256) {
            int blkid = fi >> 6, fl = fi & 63;
            int dn = blkid >> 1, ks = blkid & 1;
            int d = dn * 16 + (fl & 15);
            int kq = fl >> 4;
            short8 v;
            #pragma unroll
            for (int j = 0; j < 8; ++j) {
                int gk = kc + ks * 32 + kq * 8 + j;
                short sv = 0;
                if (d < 72 && gk <= 256) {
                    if (gk == 0) sv = *(const short*)(eksb ? &evsb[ctxbase + d] : nullptr);
                    else sv = *(const short*)&qkv[qkvbase + (long)(gk - 1) * 3456 + 2304 + hoff + d];
                }
                v[j] = sv;
            }
            *(short8*)&vT[blkid * 512 + fl * 8] = v;
        }
        __syncthreads();

        // ---- QK^T (scores in C-layout regs) ----
        floatx4 sacc[4] = {};
        #pragma unroll
        for (int nt = 0; nt < 4; ++nt) {
            int key = kc + nt * 16 + col;
            #pragma unroll
            for (int ks = 0; ks < 3; ++ks) {
                int k0 = ks * 32 + q * 8;
                short8 kf = {0,0,0,0,0,0,0,0};
                if (key <= 256 && k0 + 8 <= 72) {
                    if (key == 0) kf = *(const short8*)(eksb + ctxbase + k0);
                    else kf = *(const short8*)(qkv + qkvbase + (long)(key - 1) * 3456 + 1152 + hoff + k0);
                }
                sacc[nt] = __builtin_amdgcn_mfma_f32_16x16x32_bf16(qf[ks], kf, sacc[nt], 0, 0, 0);
            }
        }

        // ---- online softmax (row = q*4+r, cols across 16 lanes) ----
        float p[4][4];
        #pragma unroll
        for (int r = 0; r < 4; ++r) {
            float mv = -1e30f;
            #pragma unroll
            for (int nt = 0; nt < 4; ++nt) {
                int key = kc + nt * 16 + col;
                float s = (key <= 256) ? sacc[nt][r] * SCALE_ : -1e30f;
                p[nt][r] = s;
                mv = fmaxf(mv, s);
            }
            #pragma unroll
            for (int xm = 1; xm < 16; xm <<= 1) mv = fmaxf(mv, __shfl_xor(mv, xm));
            float mn = fmaxf(m_i[r], mv);
            float alpha = expf(m_i[r] - mn);
            m_i[r] = mn;
            float rsum = 0.f;
            #pragma unroll
            for (int nt = 0; nt < 4; ++nt) {
                float e = expf(p[nt][r] - mn);
                p[nt][r] = e;
                rsum += e;
            }
            #pragma unroll
            for (int xm = 1; xm < 16; xm <<= 1) rsum += __shfl_xor(rsum, xm);
            l_i[r] = l_i[r] * alpha + rsum;
            #pragma unroll
            for (int dn = 0; dn < 5; ++dn) o[dn][r] *= alpha;
        }

        // ---- P (bf16) -> per-wave frag-linear LDS ----
        #pragma unroll
        for (int nt = 0; nt < 4; ++nt) {
            int kl = nt * 16 + col;
            int ks2 = kl >> 5, q2 = (kl >> 3) & 3, j = kl & 7;
            #pragma unroll
            for (int r = 0; r < 4; ++r) {
                int mrow = q * 4 + r;
                pl[wave][ks2 * 512 + q2 * 128 + mrow * 8 + j] = f2bs(p[nt][r]);
            }
        }
        __syncthreads();

        // ---- PV ----
        #pragma unroll
        for (int ks = 0; ks < 2; ++ks) {
            short8 pf = *(const short8*)&pl[wave][ks * 512 + lane * 8];
            #pragma unroll
            for (int dn = 0; dn < 5; ++dn) {
                short8 vf = *(const short8*)&vT[(dn * 2 + ks) * 512 + lane * 8];
                o[dn] = __builtin_amdgcn_mfma_f32_16x16x32_bf16(pf, vf, o[dn], 0, 0, 0);
            }
        }
        __syncthreads();
    }

    // ---- epilogue: O / l ----
    int orow0 = ic * 64 + wave * 16;
    #pragma unroll
    for (int dn = 0; dn < 5; ++dn) {
        int d = dn * 16 + col;
        if (d >= 72) continue;
        #pragma unroll
        for (int r = 0; r < 4; ++r) {
            int mrow = q * 4 + r;
            float val = o[dn][r] / l_i[r];
            out[((long)bt * 256 + orow0 + mrow) * 1152 + hoff + d] = __float2bfloat16(val);
        }
    }
}

// ---------------- x4 = x + res (res rows are (b,n,t)) ----------------
template<int MODE>
__global__ __launch_bounds__(256) void k_add_t(
    const void* __restrict__ x, const float* __restrict__ res,
    float* __restrict__ x4, const int* __restrict__ flg)
{
    if (*flg != MODE) return;
    int idx = blockIdx.x * 256 + threadIdx.x;
    int r = idx / 1152;
    int mcol = idx - r * 1152;
    int n = r & 255;
    int bt = r >> 8;
    int b = bt >> 4, t = bt & 15;
    long r2 = (long)((b << 8) + n) * 16 + t;
    x4[idx] = ldin<MODE>(x, idx) + res[r2 * 1152 + mcol];
}

// ---------------- x4 += gate * y ; optionally emit output ----------------
template<int MODE>
__global__ __launch_bounds__(256) void k_add_g(
    float* __restrict__ x4, const float* __restrict__ y,
    const float* __restrict__ ada, int part, void* __restrict__ outp,
    const int* __restrict__ flg)
{
    if (*flg != MODE) return;
    int idx = blockIdx.x * 256 + threadIdx.x;
    int r = idx / 1152;
    int mcol = idx - r * 1152;
    int b = r >> 12;
    float g = ada[(b * 6 + part) * 1152 + mcol];
    float v = x4[idx] + g * y[idx];
    x4[idx] = v;
    if (outp) {
        if (MODE == 0) ((bf16*)outp)[idx] = __float2bfloat16(v);
        else           ((float*)outp)[idx] = v;
    }
}

extern "C" void kernel_launch(void* const* d_in, const int* in_sizes, int n_in,
                              void* d_out, int out_size, void* d_ws, size_t ws_size,
                              hipStream_t stream)
{
    const void* x      = d_in[0];
    const void* c4t    = d_in[1];
    const void* c      = d_in[2];
    const void* W_ada  = d_in[3];
    const void* b_ada  = d_in[4];
    const void* tn_w   = d_in[5];
    const void* tn_b   = d_in[6];
    const void* t_qkv  = d_in[7];
    const void* t_k    = d_in[8];
    const void* t_v    = d_in[9];
    const void* t_outw = d_in[10];
    const void* t_fcw  = d_in[11];
    const void* t_fcb  = d_in[12];
    const void* s_qkv  = d_in[13];
    const void* s_k    = d_in[14];
    const void* s_v    = d_in[15];
    const void* s_outw = d_in[16];
    const void* mlp_w1 = d_in[17];
    const void* mlp_b1 = d_in[18];
    const void* mlp_w2 = d_in[19];
    const void* mlp_b2 = d_in[20];
    const int*  f      = (const int*)d_in[21];

    float* ws    = (float*)d_ws;
    float* x4    = ws;                        //  9,437,184 f32
    float* buf2  = x4 + 9437184;              //  9,437,184 f32
    float* reg1f = buf2 + 9437184;            // 18,874,368 f32-slots
    bf16*  qkvb  = (bf16*)reg1f;
    bf16*  hbf   = (bf16*)reg1f;
    float* abfAf = reg1f + 18874368;          //  4,718,592 f32-slots
    bf16*  abfA  = (bf16*)abfAf;
    float* abfBf = abfAf + 4718592;           //  4,718,592 f32-slots
    bf16*  abfB  = (bf16*)abfBf;
    float* wtf   = abfBf + 4718592;           // 11,280,384 f32-slots
    bf16*  wt    = (bf16*)wtf;
    bf16* t_qkv_t = wt;
    bf16* s_qkv_t = t_qkv_t + 3981312;
    bf16* t_out_t = s_qkv_t + 3981312;
    bf16* t_fc_t  = t_out_t + 1327104;
    bf16* s_out_t = t_fc_t  + 1327104;
    bf16* w1_t    = s_out_t + 1327104;
    bf16* w2_t    = w1_t    + 5308416;
    float* small  = wtf + 11280384;
    float* ada   = small;                      // 13,824
    float* cf32  = ada  + 13824;               // 36,864
    float* ekt   = cf32 + 36864;
    float* evt   = ekt  + 36864;
    float* eks   = evt  + 36864;
    float* evs   = eks  + 36864;
    bf16*  eksb  = (bf16*)(evs + 36864);       // 36,864 bf16 -> 18,432 f32 slots
    bf16*  evsb  = eksb + 36864;               // 36,864 bf16
    float* sc4   = (float*)(evsb + 36864);     // 2,304
    float* fcb_f = sc4  + 2304;
    float* b1_f  = fcb_f + 1152;
    float* b2_f  = b1_f  + 4608;
    float* ropeC = b2_f + 1152;
    float* ropeS = ropeC + 1152;
    int*   flg   = (int*)(ropeS + 1152);

    k_detect<<<1, 64, 0, stream>>>(x, flg);
    k_rope<<<5, 256, 0, stream>>>(f, ropeC, ropeS);

    // ---- modulation ----
    k_silu<0><<<9, 256, 0, stream>>>(c4t, sc4, flg);
    k_silu<1><<<9, 256, 0, stream>>>(c4t, sc4, flg);
    k_gemm<0><<<dim3(108, 1), 256, 0, stream>>>(sc4, W_ada, b_ada, ada, 2, 1152, 6912, 0, flg);
    k_gemm<1><<<dim3(108, 1), 256, 0, stream>>>(sc4, W_ada, b_ada, ada, 2, 1152, 6912, 0, flg);

    // ---- context projections ----
    k_cvt<0><<<144, 256, 0, stream>>>(c, cf32, 36864, flg);
    k_cvt<1><<<144, 256, 0, stream>>>(c, cf32, 36864, flg);
    k_gemm<0><<<dim3(18, 1), 256, 0, stream>>>(cf32, t_k, nullptr, ekt, 32, 1152, 1152, 0, flg);
    k_gemm<1><<<dim3(18, 1), 256, 0, stream>>>(cf32, t_k, nullptr, ekt, 32, 1152, 1152, 0, flg);
    k_gemm<0><<<dim3(18, 1), 256, 0, stream>>>(cf32, t_v, nullptr, evt, 32, 1152, 1152, 0, flg);
    k_gemm<1><<<dim3(18, 1), 256, 0, stream>>>(cf32, t_v, nullptr, evt, 32, 1152, 1152, 0, flg);
    k_gemm<0><<<dim3(18, 1), 256, 0, stream>>>(cf32, s_k, nullptr, eks, 32, 1152, 1152, 0, flg);
    k_gemm<1><<<dim3(18, 1), 256, 0, stream>>>(cf32, s_k, nullptr, eks, 32, 1152, 1152, 0, flg);
    k_gemm<0><<<dim3(18, 1), 256, 0, stream>>>(cf32, s_v, nullptr, evs, 32, 1152, 1152, 0, flg);
    k_gemm<1><<<dim3(18, 1), 256, 0, stream>>>(cf32, s_v, nullptr, evs, 32, 1152, 1152, 0, flg);
    k_cvtb<<<144, 256, 0, stream>>>(eks, eksb, 36864);
    k_cvtb<<<144, 256, 0, stream>>>(evs, evsb, 36864);

    // ---- bias converts ----
    k_cvt<0><<<5, 256, 0, stream>>>(t_fcb, fcb_f, 1152, flg);
    k_cvt<1><<<5, 256, 0, stream>>>(t_fcb, fcb_f, 1152, flg);
    k_cvt<0><<<18, 256, 0, stream>>>(mlp_b1, b1_f, 4608, flg);
    k_cvt<1><<<18, 256, 0, stream>>>(mlp_b1, b1_f, 4608, flg);
    k_cvt<0><<<5, 256, 0, stream>>>(mlp_b2, b2_f, 1152, flg);
    k_cvt<1><<<5, 256, 0, stream>>>(mlp_b2, b2_f, 1152, flg);

    // ---- weight transpose+convert ----
    k_wt<0><<<dim3(108, 36), 256, 0, stream>>>(t_qkv, t_qkv_t, 1152, 3456, flg);
    k_wt<1><<<dim3(108, 36), 256, 0, stream>>>(t_qkv, t_qkv_t, 1152, 3456, flg);
    k_wt<0><<<dim3(108, 36), 256, 0, stream>>>(s_qkv, s_qkv_t, 1152, 3456, flg);
    k_wt<1><<<dim3(108, 36), 256, 0, stream>>>(s_qkv, s_qkv_t, 1152, 3456, flg);
    k_wt<0><<<dim3(36, 36), 256, 0, stream>>>(t_outw, t_out_t, 1152, 1152, flg);
    k_wt<1><<<dim3(36, 36), 256, 0, stream>>>(t_outw, t_out_t, 1152, 1152, flg);
    k_wt<0><<<dim3(36, 36), 256, 0, stream>>>(t_fcw, t_fc_t, 1152, 1152, flg);
    k_wt<1><<<dim3(36, 36), 256, 0, stream>>>(t_fcw, t_fc_t, 1152, 1152, flg);
    k_wt<0><<<dim3(36, 36), 256, 0, stream>>>(s_outw, s_out_t, 1152, 1152, flg);
    k_wt<1><<<dim3(36, 36), 256, 0, stream>>>(s_outw, s_out_t, 1152, 1152, flg);
    k_wt<0><<<dim3(144, 36), 256, 0, stream>>>(mlp_w1, w1_t, 1152, 4608, flg);
    k_wt<1><<<dim3(144, 36), 256, 0, stream>>>(mlp_w1, w1_t, 1152, 4608, flg);
    k_wt<0><<<dim3(36, 144), 256, 0, stream>>>(mlp_w2, w2_t, 4608, 1152, flg);
    k_wt<1><<<dim3(36, 144), 256, 0, stream>>>(mlp_w2, w2_t, 4608, 1152, flg);

    // ---- temporal attention ----
    k_ln_t<0><<<8192, 256, 0, stream>>>(x, tn_w, tn_b, abfA, flg);
    k_ln_t<1><<<8192, 256, 0, stream>>>(x, tn_w, tn_b, abfA, flg);
    k_mgemm<<<dim3(27, 64), 256, 0, stream>>>(abfA, t_qkv_t, nullptr, qkvb, 1152, 3456, 1, 0);
    k_attn_t<<<8192, 256, 0, stream>>>(qkvb, ekt, evt, ropeC, ropeS, abfB);
    k_mgemm<<<dim3(9, 64), 256, 0, stream>>>(abfB, t_out_t, nullptr, abfA, 1152, 1152, 1, 0);
    k_mgemm<<<dim3(9, 64), 256, 0, stream>>>(abfA, t_fc_t, fcb_f, buf2, 1152, 1152, 0, 0);
    k_add_t<0><<<36864, 256, 0, stream>>>(x, buf2, x4, flg);
    k_add_t<1><<<36864, 256, 0, stream>>>(x, buf2, x4, flg);

    // ---- spatial attention ----
    k_ln_mod<<<8192, 256, 0, stream>>>(x4, ada, 0, 1, 1e-6f, abfA);
    k_mgemm<<<dim3(27, 64), 256, 0, stream>>>(abfA, s_qkv_t, nullptr, qkvb, 1152, 3456, 1, 0);
    k_attn_s<<<2048, 256, 0, stream>>>(qkvb, eksb, evsb, abfB);
    k_mgemm<<<dim3(9, 64), 256, 0, stream>>>(abfB, s_out_t, nullptr, buf2, 1152, 1152, 0, 0);
    k_add_g<0><<<36864, 256, 0, stream>>>(x4, buf2, ada, 2, nullptr, flg);
    k_add_g<1><<<36864, 256, 0, stream>>>(x4, buf2, ada, 2, nullptr, flg);

    // ---- MLP ----
    k_ln_mod<<<8192, 256, 0, stream>>>(x4, ada, 3, 4, 1e-6f, abfA);
    k_mgemm<<<dim3(36, 64), 256, 0, stream>>>(abfA, w1_t, b1_f, hbf, 1152, 4608, 1, 1);
    k_mgemm<<<dim3(9, 64), 256, 0, stream>>>(hbf, w2_t, b2_f, buf2, 4608, 1152, 0, 0);
    k_add_g<0><<<36864, 256, 0, stream>>>(x4, buf2, ada, 5, d_out, flg);
    k_add_g<1><<<36864, 256, 0, stream>>>(x4, buf2, ada, 5, d_out, flg);
}